// Round 1
// baseline (1878.905 us; speedup 1.0000x reference)
//
#include <hip/hip_runtime.h>
#include <math.h>

namespace {

constexpr int BB  = 32;    // batch
constexpr int LL  = 1024;  // sequence length
constexpr int INP = 600;
constexpr int HID = 200;
constexpr int RS  = BB * LL;   // 32768 rows per stream

constexpr int BM = 128, BN = 128, KT = 8;

__device__ __forceinline__ float relu(float x) { return fmaxf(x, 0.f); }

__device__ __forceinline__ void micro_8x8(const float (&sA)[KT][BM], const float (&sB)[KT][BN],
                                          float (&acc)[8][8], int tx, int ty)
{
#pragma unroll
  for (int kk = 0; kk < KT; ++kk) {
    float4 a0 = *(const float4*)&sA[kk][ty * 8];
    float4 a1 = *(const float4*)&sA[kk][ty * 8 + 4];
    float4 b0 = *(const float4*)&sB[kk][tx * 8];
    float4 b1 = *(const float4*)&sB[kk][tx * 8 + 4];
    float ar[8] = {a0.x, a0.y, a0.z, a0.w, a1.x, a1.y, a1.z, a1.w};
    float br[8] = {b0.x, b0.y, b0.z, b0.w, b1.x, b1.y, b1.z, b1.w};
#pragma unroll
    for (int i = 0; i < 8; ++i)
#pragma unroll
      for (int j = 0; j < 8; ++j)
        acc[i][j] = fmaf(ar[i], br[j], acc[i][j]);
  }
}

// ---------------- MLP GEMM: out[z][m][0:200] = relu(A_z[m][0:K] @ W[0:K][0:200] + bias) -------------
__global__ __launch_bounds__(256) void mlp_gemm(
    const float* __restrict__ A0, const float* __restrict__ A1,
    const float* __restrict__ W,  const float* __restrict__ bias,
    float* __restrict__ Out, int K)
{
  __shared__ __align__(16) float sA[KT][BM];
  __shared__ __align__(16) float sB[KT][BN];
  const int z = blockIdx.z;
  const float* __restrict__ A = z ? A1 : A0;
  float* __restrict__ out = Out + (size_t)z * RS * HID;
  const int m0 = blockIdx.x * BM;
  const int n0 = blockIdx.y * BN;
  const int tid = threadIdx.x;
  const int tx = tid & 15, ty = tid >> 4;
  const int am = tid & 127, akg = (tid >> 7) * 4;   // A transpose-stage: row m0+am, k-offset akg..akg+3
  const int bn = (tid & 31) * 4, bkk = tid >> 5;    // B direct stage

  float acc[8][8] = {};
  for (int k0 = 0; k0 < K; k0 += KT) {
    float4 av = *(const float4*)(A + (size_t)(m0 + am) * K + k0 + akg);
    sA[akg + 0][am] = av.x; sA[akg + 1][am] = av.y;
    sA[akg + 2][am] = av.z; sA[akg + 3][am] = av.w;
    const int gn = n0 + bn;
    float4 bv = make_float4(0.f, 0.f, 0.f, 0.f);
    if (gn < HID) bv = *(const float4*)(W + (size_t)(k0 + bkk) * HID + gn);
    *(float4*)&sB[bkk][bn] = bv;
    __syncthreads();
    micro_8x8(sA, sB, acc, tx, ty);
    __syncthreads();
  }
#pragma unroll
  for (int i = 0; i < 8; ++i) {
    const int m = m0 + ty * 8 + i;
#pragma unroll
    for (int j4 = 0; j4 < 8; j4 += 4) {
      const int n = n0 + tx * 8 + j4;
      if (n < HID) {
        float4 v;
        v.x = relu(acc[i][j4 + 0] + bias[n + 0]);
        v.y = relu(acc[i][j4 + 1] + bias[n + 1]);
        v.z = relu(acc[i][j4 + 2] + bias[n + 2]);
        v.w = relu(acc[i][j4 + 3] + bias[n + 3]);
        *(float4*)(out + (size_t)m * HID + n) = v;
      }
    }
  }
}

// ---------------- e[b][l][m] = sum_d h1[b][l][d] * h2[b][m][d] ----------------
__global__ __launch_bounds__(256) void e_gemm(
    const float* __restrict__ H1, const float* __restrict__ H2, float* __restrict__ E)
{
  __shared__ __align__(16) float sA[KT][BM];
  __shared__ __align__(16) float sB[KT][BN];
  const int b = blockIdx.z;
  const float* __restrict__ A  = H1 + (size_t)b * LL * HID;
  const float* __restrict__ Bp = H2 + (size_t)b * LL * HID;
  float* __restrict__ e = E + (size_t)b * LL * LL;
  const int l0 = blockIdx.x * BM;
  const int m0 = blockIdx.y * BN;
  const int tid = threadIdx.x;
  const int tx = tid & 15, ty = tid >> 4;
  const int rr = tid & 127, kg = (tid >> 7) * 4;

  float acc[8][8] = {};
  for (int k0 = 0; k0 < HID; k0 += KT) {
    float4 av = *(const float4*)(A + (size_t)(l0 + rr) * HID + k0 + kg);
    sA[kg + 0][rr] = av.x; sA[kg + 1][rr] = av.y;
    sA[kg + 2][rr] = av.z; sA[kg + 3][rr] = av.w;
    float4 bv = *(const float4*)(Bp + (size_t)(m0 + rr) * HID + k0 + kg);
    sB[kg + 0][rr] = bv.x; sB[kg + 1][rr] = bv.y;
    sB[kg + 2][rr] = bv.z; sB[kg + 3][rr] = bv.w;
    __syncthreads();
    micro_8x8(sA, sB, acc, tx, ty);
    __syncthreads();
  }
#pragma unroll
  for (int i = 0; i < 8; ++i) {
    float* erow = e + (size_t)(l0 + ty * 8 + i) * LL + m0 + tx * 8;
    *(float4*)(erow)     = make_float4(acc[i][0], acc[i][1], acc[i][2], acc[i][3]);
    *(float4*)(erow + 4) = make_float4(acc[i][4], acc[i][5], acc[i][6], acc[i][7]);
  }
}

// ---------------- row stats (beta softmax over m): rmax/rinv per (b,l) ----------------
__global__ __launch_bounds__(256) void row_stats(
    const float* __restrict__ E, const float* __restrict__ mask2,
    float* __restrict__ rmax, float* __restrict__ rinv)
{
  const int wid = threadIdx.x >> 6, lane = threadIdx.x & 63;
  const int r = blockIdx.x * 4 + wid;           // global row = b*1024 + l
  const int b = r >> 10;
  const float* __restrict__ row = E + (size_t)r * LL;
  const float* __restrict__ m2 = mask2 + b * LL;
  float v[16];
  float mx = -INFINITY;
#pragma unroll
  for (int i = 0; i < 4; ++i) {
    const int m = lane * 4 + i * 256;
    float4 e4 = *(const float4*)(row + m);
    float4 k4 = *(const float4*)(m2 + m);
    v[i * 4 + 0] = e4.x * k4.x; v[i * 4 + 1] = e4.y * k4.y;
    v[i * 4 + 2] = e4.z * k4.z; v[i * 4 + 3] = e4.w * k4.w;
    mx = fmaxf(mx, fmaxf(fmaxf(v[i * 4], v[i * 4 + 1]), fmaxf(v[i * 4 + 2], v[i * 4 + 3])));
  }
#pragma unroll
  for (int off = 32; off; off >>= 1) mx = fmaxf(mx, __shfl_xor(mx, off));
  float s = 0.f;
#pragma unroll
  for (int i = 0; i < 16; ++i) s += __expf(v[i] - mx);
#pragma unroll
  for (int off = 32; off; off >>= 1) s += __shfl_xor(s, off);
  if (lane == 0) { rmax[r] = mx; rinv[r] = 1.f / s; }
}

// ---------------- column stats (alpha softmax over l), pass 1: partials over l-chunks --------------
__global__ __launch_bounds__(256) void col_stats_p1(
    const float* __restrict__ E, const float* __restrict__ mask1,
    float* __restrict__ pmax, float* __restrict__ psum)
{
  const int b = blockIdx.z, lc = blockIdx.y;
  const int m = blockIdx.x * 256 + threadIdx.x;
  const float* __restrict__ e = E + (size_t)b * LL * LL;
  const float* __restrict__ m1 = mask1 + b * LL;
  float mx = -INFINITY, s = 0.f;
#pragma unroll 4
  for (int l = lc * 256; l < lc * 256 + 256; ++l) {
    const float v = e[(size_t)l * LL + m] * m1[l];
    if (v > mx) { s = s * __expf(mx - v) + 1.f; mx = v; }
    else        { s += __expf(v - mx); }
  }
  const int idx = (b * 4 + lc) * LL + m;
  pmax[idx] = mx; psum[idx] = s;
}

__global__ __launch_bounds__(256) void col_stats_p2(
    const float* __restrict__ pmax, const float* __restrict__ psum,
    float* __restrict__ cmax, float* __restrict__ cinv)
{
  const int b = blockIdx.y;
  const int m = blockIdx.x * 256 + threadIdx.x;
  float M = -INFINITY;
#pragma unroll
  for (int i = 0; i < 4; ++i) M = fmaxf(M, pmax[(b * 4 + i) * LL + m]);
  float S = 0.f;
#pragma unroll
  for (int i = 0; i < 4; ++i) S += psum[(b * 4 + i) * LL + m] * __expf(pmax[(b * 4 + i) * LL + m] - M);
  cmax[(size_t)b * LL + m] = M;
  cinv[(size_t)b * LL + m] = 1.f / S;
}

// ---------------- alphas[b][m][d] = (sum_l e_alpha[l][m] * s1[l][d]) * mask2[m] ----------------
// e_alpha[l][m] = exp(e[l][m]*mask1[l] - cmax[m]) * cinv[m]   (A operand is K-major: natural)
__global__ __launch_bounds__(256) void alphas_gemm(
    const float* __restrict__ E, const float* __restrict__ S1,
    const float* __restrict__ mask1, const float* __restrict__ mask2,
    const float* __restrict__ cmax, const float* __restrict__ cinv,
    float* __restrict__ OutA)
{
  __shared__ __align__(16) float sA[KT][BM];
  __shared__ __align__(16) float sB[KT][BN];
  __shared__ __align__(16) float s_cm[BM], s_ci[BM], s_m2[BM];
  const int b = blockIdx.z;
  const float* __restrict__ e  = E  + (size_t)b * LL * LL;
  const float* __restrict__ s1 = S1 + (size_t)b * LL * INP;
  const int m0 = blockIdx.x * BM;
  const int d0 = blockIdx.y * BN;
  const int tid = threadIdx.x;
  const int tx = tid & 15, ty = tid >> 4;
  if (tid < BM) {
    s_cm[tid] = cmax[b * LL + m0 + tid];
    s_ci[tid] = cinv[b * LL + m0 + tid];
    s_m2[tid] = mask2[b * LL + m0 + tid];
  }
  __syncthreads();
  const int cc = (tid & 31) * 4, kk_ = tid >> 5;

  float acc[8][8] = {};
  for (int k0 = 0; k0 < LL; k0 += KT) {
    const int l = k0 + kk_;
    const float mk = mask1[b * LL + l];
    float4 ev = *(const float4*)(e + (size_t)l * LL + m0 + cc);
    float4 av;
    av.x = __expf(ev.x * mk - s_cm[cc + 0]) * s_ci[cc + 0];
    av.y = __expf(ev.y * mk - s_cm[cc + 1]) * s_ci[cc + 1];
    av.z = __expf(ev.z * mk - s_cm[cc + 2]) * s_ci[cc + 2];
    av.w = __expf(ev.w * mk - s_cm[cc + 3]) * s_ci[cc + 3];
    *(float4*)&sA[kk_][cc] = av;
    const int gd = d0 + cc;
    float4 bv = make_float4(0.f, 0.f, 0.f, 0.f);
    if (gd < INP) bv = *(const float4*)(s1 + (size_t)l * INP + gd);
    *(float4*)&sB[kk_][cc] = bv;
    __syncthreads();
    micro_8x8(sA, sB, acc, tx, ty);
    __syncthreads();
  }
#pragma unroll
  for (int i = 0; i < 8; ++i) {
    const int m = m0 + ty * 8 + i;
    const float mm = s_m2[ty * 8 + i];
    float* orow = OutA + ((size_t)b * LL + m) * INP;
#pragma unroll
    for (int j4 = 0; j4 < 8; j4 += 4) {
      const int d = d0 + tx * 8 + j4;
      if (d < INP) {
        *(float4*)(orow + d) = make_float4(acc[i][j4] * mm, acc[i][j4 + 1] * mm,
                                           acc[i][j4 + 2] * mm, acc[i][j4 + 3] * mm);
      }
    }
  }
}

// ---------------- betas[b][l][d] = (sum_m e_beta[l][m] * s2[m][d]) * mask1[l] ----------------
// e_beta[l][m] = exp(e[l][m]*mask2[m] - rmax[l]) * rinv[l]   (A operand is M-major: transpose-stage)
__global__ __launch_bounds__(256) void betas_gemm(
    const float* __restrict__ E, const float* __restrict__ S2,
    const float* __restrict__ mask1, const float* __restrict__ mask2,
    const float* __restrict__ rmax, const float* __restrict__ rinv,
    float* __restrict__ OutB)
{
  __shared__ __align__(16) float sA[KT][BM];
  __shared__ __align__(16) float sB[KT][BN];
  __shared__ __align__(16) float s_rm[BM], s_ri[BM], s_m1[BM];
  const int b = blockIdx.z;
  const float* __restrict__ e  = E  + (size_t)b * LL * LL;
  const float* __restrict__ s2 = S2 + (size_t)b * LL * INP;
  const int l0 = blockIdx.x * BM;
  const int d0 = blockIdx.y * BN;
  const int tid = threadIdx.x;
  const int tx = tid & 15, ty = tid >> 4;
  if (tid < BM) {
    s_rm[tid] = rmax[b * LL + l0 + tid];
    s_ri[tid] = rinv[b * LL + l0 + tid];
    s_m1[tid] = mask1[b * LL + l0 + tid];
  }
  __syncthreads();
  const int al = tid & 127, akg = (tid >> 7) * 4;
  const int cc = (tid & 31) * 4, kk_ = tid >> 5;

  float acc[8][8] = {};
  for (int k0 = 0; k0 < LL; k0 += KT) {
    float4 ev = *(const float4*)(e + (size_t)(l0 + al) * LL + k0 + akg);
    float4 mk = *(const float4*)(mask2 + b * LL + k0 + akg);
    const float rm = s_rm[al], ri = s_ri[al];
    sA[akg + 0][al] = __expf(ev.x * mk.x - rm) * ri;
    sA[akg + 1][al] = __expf(ev.y * mk.y - rm) * ri;
    sA[akg + 2][al] = __expf(ev.z * mk.z - rm) * ri;
    sA[akg + 3][al] = __expf(ev.w * mk.w - rm) * ri;
    const int gd = d0 + cc;
    float4 bv = make_float4(0.f, 0.f, 0.f, 0.f);
    if (gd < INP) bv = *(const float4*)(s2 + (size_t)(k0 + kk_) * INP + gd);
    *(float4*)&sB[kk_][cc] = bv;
    __syncthreads();
    micro_8x8(sA, sB, acc, tx, ty);
    __syncthreads();
  }
#pragma unroll
  for (int i = 0; i < 8; ++i) {
    const int l = l0 + ty * 8 + i;
    const float mm = s_m1[ty * 8 + i];
    float* orow = OutB + ((size_t)b * LL + l) * INP;
#pragma unroll
    for (int j4 = 0; j4 < 8; j4 += 4) {
      const int d = d0 + tx * 8 + j4;
      if (d < INP) {
        *(float4*)(orow + d) = make_float4(acc[i][j4] * mm, acc[i][j4 + 1] * mm,
                                           acc[i][j4 + 2] * mm, acc[i][j4 + 3] * mm);
      }
    }
  }
}

} // namespace

extern "C" void kernel_launch(void* const* d_in, const int* in_sizes, int n_in,
                              void* d_out, int out_size, void* d_ws, size_t ws_size,
                              hipStream_t stream)
{
  const float* s1    = (const float*)d_in[0];
  const float* s2    = (const float*)d_in[1];
  const float* mask1 = (const float*)d_in[2];
  const float* mask2 = (const float*)d_in[3];
  const float* W1    = (const float*)d_in[4];
  const float* b1    = (const float*)d_in[5];
  const float* W2    = (const float*)d_in[6];
  const float* b2    = (const float*)d_in[7];

  float* ws = (float*)d_ws;
  // Workspace layout (floats):
  //   h    [2][RS][HID]        @ 0                (13,107,200)
  //   hmid [2][RS][HID]        @ 13,107,200       (13,107,200)  -- dead after layer2
  //   E    [BB][LL][LL]        @ 13,107,200       (33,554,432)  -- reuses hmid region
  //   stats                    @ 46,661,632       (393,216)
  // Peak = 47,054,848 floats = 188.2 MB
  float* h    = ws;
  float* hmid = ws + (size_t)2 * RS * HID;
  float* E    = hmid;
  float* stats = ws + (size_t)2 * RS * HID + (size_t)BB * LL * LL;
  float* rmax = stats;
  float* rinv = rmax + RS;
  float* cmax = rinv + RS;
  float* cinv = cmax + RS;
  float* pmax = cinv + RS;
  float* psum = pmax + (size_t)BB * 4 * LL;

  float* outA = (float*)d_out;
  float* outB = outA + (size_t)BB * LL * INP;

  // 1) hmid = relu(s @ W1 + b1) for both streams
  mlp_gemm<<<dim3(RS / BM, 2, 2), 256, 0, stream>>>(s1, s2, W1, b1, hmid, INP);
  // 2) h = relu(hmid @ W2 + b2)
  mlp_gemm<<<dim3(RS / BM, 2, 2), 256, 0, stream>>>(hmid, hmid + (size_t)RS * HID, W2, b2, h, HID);
  // 3) e = h1 @ h2^T per batch
  e_gemm<<<dim3(LL / BM, LL / BN, BB), 256, 0, stream>>>(h, h + (size_t)RS * HID, E);
  // 4) softmax stats
  row_stats<<<dim3(RS / 4), 256, 0, stream>>>(E, mask2, rmax, rinv);
  col_stats_p1<<<dim3(4, 4, BB), 256, 0, stream>>>(E, mask1, pmax, psum);
  col_stats_p2<<<dim3(4, BB), 256, 0, stream>>>(pmax, psum, cmax, cinv);
  // 5) outputs
  alphas_gemm<<<dim3(LL / BM, (INP + BN - 1) / BN, BB), 256, 0, stream>>>(
      E, s1, mask1, mask2, cmax, cinv, outA);
  betas_gemm<<<dim3(LL / BM, (INP + BN - 1) / BN, BB), 256, 0, stream>>>(
      E, s2, mask1, mask2, rmax, rinv, outB);

  (void)in_sizes; (void)n_in; (void)out_size; (void)ws_size;
}

// Round 2
// 1130.274 us; speedup vs baseline: 1.6623x; 1.6623x over previous
//
#include <hip/hip_runtime.h>
#include <hip/hip_bf16.h>
#include <math.h>

namespace {

constexpr int BB  = 32;    // batch
constexpr int LL  = 1024;  // sequence length
constexpr int INP = 600;
constexpr int HID = 200;
constexpr int RS  = BB * LL;   // 32768 rows per stream
constexpr int DPAD = 640;      // padded d-dim for bf16 transposed s

constexpr int BM = 128, BN = 128, KT = 8;

typedef __attribute__((ext_vector_type(8))) short short8v;  // bf16x8 fragment
typedef __attribute__((ext_vector_type(4))) float f32x4;

__device__ __forceinline__ float relu(float x) { return fmaxf(x, 0.f); }

__device__ __forceinline__ unsigned short f2bf(float x) {
  union { float f; unsigned int u; } v; v.f = x;
  unsigned int r = v.u + 0x7FFFu + ((v.u >> 16) & 1u);   // RNE
  return (unsigned short)(r >> 16);
}

__device__ __forceinline__ void micro_8x8(const float (&sA)[KT][BM], const float (&sB)[KT][BN],
                                          float (&acc)[8][8], int tx, int ty)
{
#pragma unroll
  for (int kk = 0; kk < KT; ++kk) {
    float4 a0 = *(const float4*)&sA[kk][ty * 8];
    float4 a1 = *(const float4*)&sA[kk][ty * 8 + 4];
    float4 b0 = *(const float4*)&sB[kk][tx * 8];
    float4 b1 = *(const float4*)&sB[kk][tx * 8 + 4];
    float ar[8] = {a0.x, a0.y, a0.z, a0.w, a1.x, a1.y, a1.z, a1.w};
    float br[8] = {b0.x, b0.y, b0.z, b0.w, b1.x, b1.y, b1.z, b1.w};
#pragma unroll
    for (int i = 0; i < 8; ++i)
#pragma unroll
      for (int j = 0; j < 8; ++j)
        acc[i][j] = fmaf(ar[i], br[j], acc[i][j]);
  }
}

// ---------------- MLP GEMM (fp32): out = relu(A @ W + bias) ----------------
__global__ __launch_bounds__(256) void mlp_gemm(
    const float* __restrict__ A0, const float* __restrict__ A1,
    const float* __restrict__ W,  const float* __restrict__ bias,
    float* __restrict__ Out, int K)
{
  __shared__ __align__(16) float sA[KT][BM];
  __shared__ __align__(16) float sB[KT][BN];
  const int z = blockIdx.z;
  const float* __restrict__ A = z ? A1 : A0;
  float* __restrict__ out = Out + (size_t)z * RS * HID;
  const int m0 = blockIdx.x * BM;
  const int n0 = blockIdx.y * BN;
  const int tid = threadIdx.x;
  const int tx = tid & 15, ty = tid >> 4;
  const int am = tid & 127, akg = (tid >> 7) * 4;
  const int bn = (tid & 31) * 4, bkk = tid >> 5;

  float acc[8][8] = {};
  for (int k0 = 0; k0 < K; k0 += KT) {
    float4 av = *(const float4*)(A + (size_t)(m0 + am) * K + k0 + akg);
    sA[akg + 0][am] = av.x; sA[akg + 1][am] = av.y;
    sA[akg + 2][am] = av.z; sA[akg + 3][am] = av.w;
    const int gn = n0 + bn;
    float4 bv = make_float4(0.f, 0.f, 0.f, 0.f);
    if (gn < HID) bv = *(const float4*)(W + (size_t)(k0 + bkk) * HID + gn);
    *(float4*)&sB[bkk][bn] = bv;
    __syncthreads();
    micro_8x8(sA, sB, acc, tx, ty);
    __syncthreads();
  }
#pragma unroll
  for (int i = 0; i < 8; ++i) {
    const int m = m0 + ty * 8 + i;
#pragma unroll
    for (int j4 = 0; j4 < 8; j4 += 4) {
      const int n = n0 + tx * 8 + j4;
      if (n < HID) {
        float4 v;
        v.x = relu(acc[i][j4 + 0] + bias[n + 0]);
        v.y = relu(acc[i][j4 + 1] + bias[n + 1]);
        v.z = relu(acc[i][j4 + 2] + bias[n + 2]);
        v.w = relu(acc[i][j4 + 3] + bias[n + 3]);
        *(float4*)(out + (size_t)m * HID + n) = v;
      }
    }
  }
}

// ---------------- e[b][l][m] = sum_d h1[b][l][d] * h2[b][m][d]  (fp32) ----------------
__global__ __launch_bounds__(256) void e_gemm(
    const float* __restrict__ H1, const float* __restrict__ H2, float* __restrict__ E)
{
  __shared__ __align__(16) float sA[KT][BM];
  __shared__ __align__(16) float sB[KT][BN];
  const int b = blockIdx.z;
  const float* __restrict__ A  = H1 + (size_t)b * LL * HID;
  const float* __restrict__ Bp = H2 + (size_t)b * LL * HID;
  float* __restrict__ e = E + (size_t)b * LL * LL;
  const int l0 = blockIdx.x * BM;
  const int m0 = blockIdx.y * BN;
  const int tid = threadIdx.x;
  const int tx = tid & 15, ty = tid >> 4;
  const int rr = tid & 127, kg = (tid >> 7) * 4;

  float acc[8][8] = {};
  for (int k0 = 0; k0 < HID; k0 += KT) {
    float4 av = *(const float4*)(A + (size_t)(l0 + rr) * HID + k0 + kg);
    sA[kg + 0][rr] = av.x; sA[kg + 1][rr] = av.y;
    sA[kg + 2][rr] = av.z; sA[kg + 3][rr] = av.w;
    float4 bv = *(const float4*)(Bp + (size_t)(m0 + rr) * HID + k0 + kg);
    sB[kg + 0][rr] = bv.x; sB[kg + 1][rr] = bv.y;
    sB[kg + 2][rr] = bv.z; sB[kg + 3][rr] = bv.w;
    __syncthreads();
    micro_8x8(sA, sB, acc, tx, ty);
    __syncthreads();
  }
#pragma unroll
  for (int i = 0; i < 8; ++i) {
    float* erow = e + (size_t)(l0 + ty * 8 + i) * LL + m0 + tx * 8;
    *(float4*)(erow)     = make_float4(acc[i][0], acc[i][1], acc[i][2], acc[i][3]);
    *(float4*)(erow + 4) = make_float4(acc[i][4], acc[i][5], acc[i][6], acc[i][7]);
  }
}

// ---------------- row stats (beta softmax over m): rmax/rinv per (b,l) ----------------
__global__ __launch_bounds__(256) void row_stats(
    const float* __restrict__ E, const float* __restrict__ mask2,
    float* __restrict__ rmax, float* __restrict__ rinv)
{
  const int wid = threadIdx.x >> 6, lane = threadIdx.x & 63;
  const int r = blockIdx.x * 4 + wid;
  const int b = r >> 10;
  const float* __restrict__ row = E + (size_t)r * LL;
  const float* __restrict__ m2 = mask2 + b * LL;
  float v[16];
  float mx = -INFINITY;
#pragma unroll
  for (int i = 0; i < 4; ++i) {
    const int m = lane * 4 + i * 256;
    float4 e4 = *(const float4*)(row + m);
    float4 k4 = *(const float4*)(m2 + m);
    v[i * 4 + 0] = e4.x * k4.x; v[i * 4 + 1] = e4.y * k4.y;
    v[i * 4 + 2] = e4.z * k4.z; v[i * 4 + 3] = e4.w * k4.w;
    mx = fmaxf(mx, fmaxf(fmaxf(v[i * 4], v[i * 4 + 1]), fmaxf(v[i * 4 + 2], v[i * 4 + 3])));
  }
#pragma unroll
  for (int off = 32; off; off >>= 1) mx = fmaxf(mx, __shfl_xor(mx, off));
  float s = 0.f;
#pragma unroll
  for (int i = 0; i < 16; ++i) s += __expf(v[i] - mx);
#pragma unroll
  for (int off = 32; off; off >>= 1) s += __shfl_xor(s, off);
  if (lane == 0) { rmax[r] = mx; rinv[r] = 1.f / s; }
}

// ---------------- column stats (alpha softmax over l), two-pass ----------------
__global__ __launch_bounds__(256) void col_stats_p1(
    const float* __restrict__ E, const float* __restrict__ mask1,
    float* __restrict__ pmax, float* __restrict__ psum)
{
  const int b = blockIdx.z, lc = blockIdx.y;
  const int m = blockIdx.x * 256 + threadIdx.x;
  const float* __restrict__ e = E + (size_t)b * LL * LL;
  const float* __restrict__ m1 = mask1 + b * LL;
  float mx = -INFINITY, s = 0.f;
#pragma unroll 4
  for (int l = lc * 256; l < lc * 256 + 256; ++l) {
    const float v = e[(size_t)l * LL + m] * m1[l];
    if (v > mx) { s = s * __expf(mx - v) + 1.f; mx = v; }
    else        { s += __expf(v - mx); }
  }
  const int idx = (b * 4 + lc) * LL + m;
  pmax[idx] = mx; psum[idx] = s;
}

__global__ __launch_bounds__(256) void col_stats_p2(
    const float* __restrict__ pmax, const float* __restrict__ psum,
    float* __restrict__ cmax, float* __restrict__ cinv)
{
  const int b = blockIdx.y;
  const int m = blockIdx.x * 256 + threadIdx.x;
  float M = -INFINITY;
#pragma unroll
  for (int i = 0; i < 4; ++i) M = fmaxf(M, pmax[(b * 4 + i) * LL + m]);
  float S = 0.f;
#pragma unroll
  for (int i = 0; i < 4; ++i) S += psum[(b * 4 + i) * LL + m] * __expf(pmax[(b * 4 + i) * LL + m] - M);
  cmax[(size_t)b * LL + m] = M;
  cinv[(size_t)b * LL + m] = 1.f / S;
}

// ---------------- P_beta[l][m] = exp(E*mask2[m]-rmax[l])*rinv[l]  (bf16, natural layout) -------
__global__ __launch_bounds__(256) void pbeta_kernel(
    const float* __restrict__ E, const float* __restrict__ mask2,
    const float* __restrict__ rmax, const float* __restrict__ rinv,
    unsigned short* __restrict__ Pb)
{
  const int l = blockIdx.x, b = blockIdx.y;
  const int m = threadIdx.x * 4;
  const size_t rowo = ((size_t)b * LL + l) * LL;
  const float rm = rmax[b * LL + l];
  const float ri = rinv[b * LL + l];
  float4 ev = *(const float4*)(E + rowo + m);
  float4 mk = *(const float4*)(mask2 + b * LL + m);
  ushort4 o;
  o.x = f2bf(__expf(ev.x * mk.x - rm) * ri);
  o.y = f2bf(__expf(ev.y * mk.y - rm) * ri);
  o.z = f2bf(__expf(ev.z * mk.z - rm) * ri);
  o.w = f2bf(__expf(ev.w * mk.w - rm) * ri);
  *(ushort4*)(Pb + rowo + m) = o;
}

// ---------------- P_alpha[m][l] = exp(E[l][m]*mask1[l]-cmax[m])*cinv[m]  (bf16, transposed) ----
__global__ __launch_bounds__(256) void palpha_kernel(
    const float* __restrict__ E, const float* __restrict__ mask1,
    const float* __restrict__ cmax, const float* __restrict__ cinv,
    unsigned short* __restrict__ Pa)
{
  __shared__ float T[64][65];
  const int b = blockIdx.z;
  const int l0 = blockIdx.y * 64, m0 = blockIdx.x * 64;
  const int tid = threadIdx.x;
  const int rr = tid >> 4, c4 = (tid & 15) * 4;
  const float4 cm = *(const float4*)(cmax + b * LL + m0 + c4);
  const float4 ci = *(const float4*)(cinv + b * LL + m0 + c4);
#pragma unroll
  for (int it = 0; it < 4; ++it) {
    const int lloc = rr + it * 16;
    const int l = l0 + lloc;
    const float mk = mask1[b * LL + l];
    const float4 ev = *(const float4*)(E + ((size_t)b * LL + l) * LL + m0 + c4);
    T[c4 + 0][lloc] = __expf(ev.x * mk - cm.x) * ci.x;
    T[c4 + 1][lloc] = __expf(ev.y * mk - cm.y) * ci.y;
    T[c4 + 2][lloc] = __expf(ev.z * mk - cm.z) * ci.z;
    T[c4 + 3][lloc] = __expf(ev.w * mk - cm.w) * ci.w;
  }
  __syncthreads();
#pragma unroll
  for (int it = 0; it < 4; ++it) {
    const int mloc = rr + it * 16;
    ushort4 o;
    o.x = f2bf(T[mloc][c4 + 0]);
    o.y = f2bf(T[mloc][c4 + 1]);
    o.z = f2bf(T[mloc][c4 + 2]);
    o.w = f2bf(T[mloc][c4 + 3]);
    *(ushort4*)(Pa + ((size_t)b * LL + m0 + mloc) * LL + l0 + c4) = o;
  }
}

// ---------------- s transpose+cast: S[b][l][0:600] fp32 -> St[b][0:640][l] bf16 ----------------
__global__ __launch_bounds__(256) void s_transpose(
    const float* __restrict__ S, unsigned short* __restrict__ St)
{
  __shared__ float T[64][65];
  const int b = blockIdx.z;
  const int l0 = blockIdx.y * 64, d0 = blockIdx.x * 64;
  const int tid = threadIdx.x;
  const int rr = tid >> 4, c4 = (tid & 15) * 4;
#pragma unroll
  for (int it = 0; it < 4; ++it) {
    const int lloc = rr + it * 16;
    const int l = l0 + lloc;
    float4 v = make_float4(0.f, 0.f, 0.f, 0.f);
    if (d0 + c4 < INP) v = *(const float4*)(S + ((size_t)b * LL + l) * INP + d0 + c4);
    T[c4 + 0][lloc] = v.x; T[c4 + 1][lloc] = v.y;
    T[c4 + 2][lloc] = v.z; T[c4 + 3][lloc] = v.w;
  }
  __syncthreads();
#pragma unroll
  for (int it = 0; it < 4; ++it) {
    const int dloc = rr + it * 16;
    ushort4 o;
    o.x = f2bf(T[dloc][c4 + 0]);
    o.y = f2bf(T[dloc][c4 + 1]);
    o.z = f2bf(T[dloc][c4 + 2]);
    o.w = f2bf(T[dloc][c4 + 3]);
    *(ushort4*)(St + ((size_t)b * DPAD + d0 + dloc) * LL + l0 + c4) = o;
  }
}

// ---------------- bf16 MFMA GEMM: Out[b][m][d] = (sum_k Ap[b][m][k]*Bt[b][d][k]) * scale[b][m] --
// Ap: [BB][1024][1024] bf16 row=M col=K; Bt: [BB][640][1024] bf16 row=N(d) col=K.
// 128x128 tile, 4 waves (2x2), BK=64, XOR-swizzled LDS, mfma_f32_16x16x32_bf16.
__global__ __launch_bounds__(256) void attn_gemm_bf16(
    const unsigned short* __restrict__ Ap, const unsigned short* __restrict__ Bt,
    const float* __restrict__ scale, float* __restrict__ Out)
{
  __shared__ int4 sA4[1024];   // 128 rows x 8 x 16B, swizzled: idx = row*8 + (kc ^ (row&7))
  __shared__ int4 sB4[1024];
  __shared__ float s_sc[128];
  const int b  = blockIdx.z;
  const int n0 = blockIdx.x * 128;
  const int m0 = blockIdx.y * 128;
  const int tid = threadIdx.x;
  const int lane = tid & 63;
  const int w = tid >> 6;
  const int wr = w >> 1, wc = w & 1;

  const unsigned short* __restrict__ A  = Ap + (size_t)b * LL * LL;
  const unsigned short* __restrict__ Bp = Bt + (size_t)b * DPAD * LL;

  if (tid < 128) s_sc[tid] = scale[b * LL + m0 + tid];

  f32x4 acc[4][4] = {{{0.f,0.f,0.f,0.f}}};
#pragma unroll
  for (int mi = 0; mi < 4; ++mi)
#pragma unroll
    for (int ni = 0; ni < 4; ++ni)
      acc[mi][ni] = (f32x4){0.f, 0.f, 0.f, 0.f};

  const int kc = tid & 7;       // 16B chunk within row
  const int rbase = tid >> 3;   // staging row base
  const int fr = lane & 15;     // fragment row (A) / col (B)
  const int kg = lane >> 4;     // k-group within fragment

  for (int k0 = 0; k0 < LL; k0 += 64) {
    __syncthreads();
#pragma unroll
    for (int it = 0; it < 4; ++it) {
      const int r = rbase + 32 * it;
      sA4[r * 8 + (kc ^ (r & 7))] = *(const int4*)(A  + (size_t)(m0 + r) * LL + k0 + kc * 8);
      sB4[r * 8 + (kc ^ (r & 7))] = *(const int4*)(Bp + (size_t)(n0 + r) * LL + k0 + kc * 8);
    }
    __syncthreads();
#pragma unroll
    for (int kk = 0; kk < 2; ++kk) {
      short8v a[4], bf[4];
#pragma unroll
      for (int mi = 0; mi < 4; ++mi) {
        const int row = wr * 64 + mi * 16 + fr;
        a[mi] = *(const short8v*)&sA4[row * 8 + ((kk * 4 + kg) ^ (row & 7))];
      }
#pragma unroll
      for (int ni = 0; ni < 4; ++ni) {
        const int row = wc * 64 + ni * 16 + fr;
        bf[ni] = *(const short8v*)&sB4[row * 8 + ((kk * 4 + kg) ^ (row & 7))];
      }
#pragma unroll
      for (int mi = 0; mi < 4; ++mi)
#pragma unroll
        for (int ni = 0; ni < 4; ++ni)
          acc[mi][ni] = __builtin_amdgcn_mfma_f32_16x16x32_bf16(a[mi], bf[ni], acc[mi][ni], 0, 0, 0);
    }
  }

  // C/D layout: col = lane&15, row = (lane>>4)*4 + reg   [HW-verified]
#pragma unroll
  for (int mi = 0; mi < 4; ++mi) {
#pragma unroll
    for (int ni = 0; ni < 4; ++ni) {
      const int col = n0 + wc * 64 + ni * 16 + fr;
      if (col < INP) {
#pragma unroll
        for (int r = 0; r < 4; ++r) {
          const int mrow = wr * 64 + mi * 16 + kg * 4 + r;
          Out[((size_t)b * LL + m0 + mrow) * INP + col] = acc[mi][ni][r] * s_sc[mrow];
        }
      }
    }
  }
}

// ---------------- fp32 fallback alphas/betas (round-1, kept in case ws is small) ---------------
__global__ __launch_bounds__(256) void alphas_gemm(
    const float* __restrict__ E, const float* __restrict__ S1,
    const float* __restrict__ mask1, const float* __restrict__ mask2,
    const float* __restrict__ cmax, const float* __restrict__ cinv,
    float* __restrict__ OutA)
{
  __shared__ __align__(16) float sA[KT][BM];
  __shared__ __align__(16) float sB[KT][BN];
  __shared__ __align__(16) float s_cm[BM], s_ci[BM], s_m2[BM];
  const int b = blockIdx.z;
  const float* __restrict__ e  = E  + (size_t)b * LL * LL;
  const float* __restrict__ s1 = S1 + (size_t)b * LL * INP;
  const int m0 = blockIdx.x * BM;
  const int d0 = blockIdx.y * BN;
  const int tid = threadIdx.x;
  const int tx = tid & 15, ty = tid >> 4;
  if (tid < BM) {
    s_cm[tid] = cmax[b * LL + m0 + tid];
    s_ci[tid] = cinv[b * LL + m0 + tid];
    s_m2[tid] = mask2[b * LL + m0 + tid];
  }
  __syncthreads();
  const int cc = (tid & 31) * 4, kk_ = tid >> 5;

  float acc[8][8] = {};
  for (int k0 = 0; k0 < LL; k0 += KT) {
    const int l = k0 + kk_;
    const float mk = mask1[b * LL + l];
    float4 ev = *(const float4*)(e + (size_t)l * LL + m0 + cc);
    float4 av;
    av.x = __expf(ev.x * mk - s_cm[cc + 0]) * s_ci[cc + 0];
    av.y = __expf(ev.y * mk - s_cm[cc + 1]) * s_ci[cc + 1];
    av.z = __expf(ev.z * mk - s_cm[cc + 2]) * s_ci[cc + 2];
    av.w = __expf(ev.w * mk - s_cm[cc + 3]) * s_ci[cc + 3];
    *(float4*)&sA[kk_][cc] = av;
    const int gd = d0 + cc;
    float4 bv = make_float4(0.f, 0.f, 0.f, 0.f);
    if (gd < INP) bv = *(const float4*)(s1 + (size_t)l * INP + gd);
    *(float4*)&sB[kk_][cc] = bv;
    __syncthreads();
    micro_8x8(sA, sB, acc, tx, ty);
    __syncthreads();
  }
#pragma unroll
  for (int i = 0; i < 8; ++i) {
    const int m = m0 + ty * 8 + i;
    const float mm = s_m2[ty * 8 + i];
    float* orow = OutA + ((size_t)b * LL + m) * INP;
#pragma unroll
    for (int j4 = 0; j4 < 8; j4 += 4) {
      const int d = d0 + tx * 8 + j4;
      if (d < INP) {
        *(float4*)(orow + d) = make_float4(acc[i][j4] * mm, acc[i][j4 + 1] * mm,
                                           acc[i][j4 + 2] * mm, acc[i][j4 + 3] * mm);
      }
    }
  }
}

__global__ __launch_bounds__(256) void betas_gemm(
    const float* __restrict__ E, const float* __restrict__ S2,
    const float* __restrict__ mask1, const float* __restrict__ mask2,
    const float* __restrict__ rmax, const float* __restrict__ rinv,
    float* __restrict__ OutB)
{
  __shared__ __align__(16) float sA[KT][BM];
  __shared__ __align__(16) float sB[KT][BN];
  __shared__ __align__(16) float s_rm[BM], s_ri[BM], s_m1[BM];
  const int b = blockIdx.z;
  const float* __restrict__ e  = E  + (size_t)b * LL * LL;
  const float* __restrict__ s2 = S2 + (size_t)b * LL * INP;
  const int l0 = blockIdx.x * BM;
  const int d0 = blockIdx.y * BN;
  const int tid = threadIdx.x;
  const int tx = tid & 15, ty = tid >> 4;
  if (tid < BM) {
    s_rm[tid] = rmax[b * LL + l0 + tid];
    s_ri[tid] = rinv[b * LL + l0 + tid];
    s_m1[tid] = mask1[b * LL + l0 + tid];
  }
  __syncthreads();
  const int al = tid & 127, akg = (tid >> 7) * 4;
  const int cc = (tid & 31) * 4, kk_ = tid >> 5;

  float acc[8][8] = {};
  for (int k0 = 0; k0 < LL; k0 += KT) {
    float4 ev = *(const float4*)(e + (size_t)(l0 + al) * LL + k0 + akg);
    float4 mk = *(const float4*)(mask2 + b * LL + k0 + akg);
    const float rm = s_rm[al], ri = s_ri[al];
    sA[akg + 0][al] = __expf(ev.x * mk.x - rm) * ri;
    sA[akg + 1][al] = __expf(ev.y * mk.y - rm) * ri;
    sA[akg + 2][al] = __expf(ev.z * mk.z - rm) * ri;
    sA[akg + 3][al] = __expf(ev.w * mk.w - rm) * ri;
    const int gd = d0 + cc;
    float4 bv = make_float4(0.f, 0.f, 0.f, 0.f);
    if (gd < INP) bv = *(const float4*)(s2 + (size_t)(k0 + kk_) * INP + gd);
    *(float4*)&sB[kk_][cc] = bv;
    __syncthreads();
    micro_8x8(sA, sB, acc, tx, ty);
    __syncthreads();
  }
#pragma unroll
  for (int i = 0; i < 8; ++i) {
    const int l = l0 + ty * 8 + i;
    const float mm = s_m1[ty * 8 + i];
    float* orow = OutB + ((size_t)b * LL + l) * INP;
#pragma unroll
    for (int j4 = 0; j4 < 8; j4 += 4) {
      const int d = d0 + tx * 8 + j4;
      if (d < INP) {
        *(float4*)(orow + d) = make_float4(acc[i][j4] * mm, acc[i][j4 + 1] * mm,
                                           acc[i][j4 + 2] * mm, acc[i][j4 + 3] * mm);
      }
    }
  }
}

} // namespace

extern "C" void kernel_launch(void* const* d_in, const int* in_sizes, int n_in,
                              void* d_out, int out_size, void* d_ws, size_t ws_size,
                              hipStream_t stream)
{
  const float* s1    = (const float*)d_in[0];
  const float* s2    = (const float*)d_in[1];
  const float* mask1 = (const float*)d_in[2];
  const float* mask2 = (const float*)d_in[3];
  const float* W1    = (const float*)d_in[4];
  const float* b1    = (const float*)d_in[5];
  const float* W2    = (const float*)d_in[6];
  const float* b2    = (const float*)d_in[7];

  char* ws = (char*)d_ws;
  float* outA = (float*)d_out;
  float* outB = outA + (size_t)BB * LL * INP;

  // -------- fast-path workspace layout (bytes) --------
  const size_t sz_h    = (size_t)2 * RS * HID * 4;          //  52,428,800
  const size_t sz_E    = (size_t)BB * LL * LL * 4;          // 134,217,728
  const size_t sz_Pa   = (size_t)BB * LL * LL * 2;          //  67,108,864
  const size_t sz_st   = (size_t)BB * DPAD * LL * 2;        //  41,943,040
  const size_t off_h    = 0;
  const size_t off_hmid = sz_h;                 // dead after mlp2
  const size_t off_E    = 2 * sz_h;             // dead after palpha
  const size_t off_Pa   = 0;                    // reuses h+hmid (after e_gemm)
  const size_t off_stats= sz_Pa;                // in the h/hmid hole after Pa
  const size_t off_s1t  = off_E;                // reuses E (after palpha)
  const size_t off_s2t  = off_E + sz_st;
  const size_t off_Pb   = off_E + sz_E;
  const size_t TOTAL    = off_Pb + sz_Pa;       // 306,184,192 B

  if (ws_size >= TOTAL) {
    float* h    = (float*)(ws + off_h);
    float* hmid = (float*)(ws + off_hmid);
    float* E    = (float*)(ws + off_E);
    float* stats = (float*)(ws + off_stats);
    float* rmax = stats;
    float* rinv = rmax + RS;
    float* cmax = rinv + RS;
    float* cinv = cmax + RS;
    float* pmax = cinv + RS;
    float* psum = pmax + (size_t)BB * 4 * LL;
    unsigned short* Pa  = (unsigned short*)(ws + off_Pa);
    unsigned short* Pb  = (unsigned short*)(ws + off_Pb);
    unsigned short* s1t = (unsigned short*)(ws + off_s1t);
    unsigned short* s2t = (unsigned short*)(ws + off_s2t);

    mlp_gemm<<<dim3(RS / BM, 2, 2), 256, 0, stream>>>(s1, s2, W1, b1, hmid, INP);
    mlp_gemm<<<dim3(RS / BM, 2, 2), 256, 0, stream>>>(hmid, hmid + (size_t)RS * HID, W2, b2, h, HID);
    e_gemm<<<dim3(LL / BM, LL / BN, BB), 256, 0, stream>>>(h, h + (size_t)RS * HID, E);
    row_stats<<<dim3(RS / 4), 256, 0, stream>>>(E, mask2, rmax, rinv);
    col_stats_p1<<<dim3(4, 4, BB), 256, 0, stream>>>(E, mask1, pmax, psum);
    col_stats_p2<<<dim3(4, BB), 256, 0, stream>>>(pmax, psum, cmax, cinv);
    pbeta_kernel<<<dim3(LL, BB), 256, 0, stream>>>(E, mask2, rmax, rinv, Pb);
    palpha_kernel<<<dim3(16, 16, BB), 256, 0, stream>>>(E, mask1, cmax, cinv, Pa);   // E dead after
    s_transpose<<<dim3(10, 16, BB), 256, 0, stream>>>(s1, s1t);
    s_transpose<<<dim3(10, 16, BB), 256, 0, stream>>>(s2, s2t);
    // betas[b][l][d] = (P_beta @ s2t^T) * mask1[l]
    attn_gemm_bf16<<<dim3(5, 8, BB), 256, 0, stream>>>(Pb, s2t, mask1, outB);
    // alphas[b][m][d] = (P_alpha @ s1t^T) * mask2[m]
    attn_gemm_bf16<<<dim3(5, 8, BB), 256, 0, stream>>>(Pa, s1t, mask2, outA);
  } else {
    // -------- fallback: round-1 fp32 path (188 MB) --------
    float* h    = (float*)ws;
    float* hmid = h + (size_t)2 * RS * HID;
    float* E    = hmid;
    float* stats = hmid + (size_t)BB * LL * LL;
    float* rmax = stats;
    float* rinv = rmax + RS;
    float* cmax = rinv + RS;
    float* cinv = cmax + RS;
    float* pmax = cinv + RS;
    float* psum = pmax + (size_t)BB * 4 * LL;

    mlp_gemm<<<dim3(RS / BM, 2, 2), 256, 0, stream>>>(s1, s2, W1, b1, hmid, INP);
    mlp_gemm<<<dim3(RS / BM, 2, 2), 256, 0, stream>>>(hmid, hmid + (size_t)RS * HID, W2, b2, h, HID);
    e_gemm<<<dim3(LL / BM, LL / BN, BB), 256, 0, stream>>>(h, h + (size_t)RS * HID, E);
    row_stats<<<dim3(RS / 4), 256, 0, stream>>>(E, mask2, rmax, rinv);
    col_stats_p1<<<dim3(4, 4, BB), 256, 0, stream>>>(E, mask1, pmax, psum);
    col_stats_p2<<<dim3(4, BB), 256, 0, stream>>>(pmax, psum, cmax, cinv);
    alphas_gemm<<<dim3(LL / BM, (INP + BN - 1) / BN, BB), 256, 0, stream>>>(
        E, s1, mask1, mask2, cmax, cinv, outA);
    betas_gemm<<<dim3(LL / BM, (INP + BN - 1) / BN, BB), 256, 0, stream>>>(
        E, s2, mask1, mask2, rmax, rinv, outB);
  }

  (void)in_sizes; (void)n_in; (void)out_size;
}

// Round 3
// 946.154 us; speedup vs baseline: 1.9858x; 1.1946x over previous
//
#include <hip/hip_runtime.h>
#include <hip/hip_bf16.h>
#include <math.h>

namespace {

constexpr int BB  = 32;    // batch
constexpr int LL  = 1024;  // sequence length
constexpr int INP = 600;
constexpr int HID = 200;
constexpr int RS  = BB * LL;   // 32768 rows per stream
constexpr int DPAD = 640;      // padded d-dim for bf16 transposed s

constexpr int BM = 128, BN = 128, KT = 8;
constexpr int LROW = 40;       // LDS row stride in ushorts (80 B = 5x16B -> conflict-free)

typedef __attribute__((ext_vector_type(8))) short short8v;  // bf16x8 fragment
typedef __attribute__((ext_vector_type(4))) float f32x4;

__device__ __forceinline__ float relu(float x) { return fmaxf(x, 0.f); }

__device__ __forceinline__ unsigned short f2bf(float x) {
  union { float f; unsigned int u; } v; v.f = x;
  unsigned int r = v.u + 0x7FFFu + ((v.u >> 16) & 1u);   // RNE
  return (unsigned short)(r >> 16);
}
__device__ __forceinline__ float bf2f(unsigned short h) {
  union { unsigned int u; float f; } v; v.u = ((unsigned int)h) << 16;
  return v.f;
}

__device__ __forceinline__ void micro_8x8(const float (&sA)[KT][BM], const float (&sB)[KT][BN],
                                          float (&acc)[8][8], int tx, int ty)
{
#pragma unroll
  for (int kk = 0; kk < KT; ++kk) {
    float4 a0 = *(const float4*)&sA[kk][ty * 8];
    float4 a1 = *(const float4*)&sA[kk][ty * 8 + 4];
    float4 b0 = *(const float4*)&sB[kk][tx * 8];
    float4 b1 = *(const float4*)&sB[kk][tx * 8 + 4];
    float ar[8] = {a0.x, a0.y, a0.z, a0.w, a1.x, a1.y, a1.z, a1.w};
    float br[8] = {b0.x, b0.y, b0.z, b0.w, b1.x, b1.y, b1.z, b1.w};
#pragma unroll
    for (int i = 0; i < 8; ++i)
#pragma unroll
      for (int j = 0; j < 8; ++j)
        acc[i][j] = fmaf(ar[i], br[j], acc[i][j]);
  }
}

// ============ W transpose + split prep: W[K][200] fp32 -> Wt_hi/lo[256][KP] bf16, zero-padded ====
__global__ __launch_bounds__(256) void wt_prep(
    const float* __restrict__ W, unsigned short* __restrict__ Whi, unsigned short* __restrict__ Wlo,
    int K, int KP)
{
  const int k = blockIdx.x * 256 + threadIdx.x;
  const int n = blockIdx.y;              // 0..255 (rows 200..255 zero)
  if (k >= KP) return;
  float v = (k < K && n < HID) ? W[(size_t)k * HID + n] : 0.f;
  unsigned short hi = f2bf(v);
  unsigned short lo = f2bf(v - bf2f(hi));
  Whi[(size_t)n * KP + k] = hi;
  Wlo[(size_t)n * KP + k] = lo;
}

// ============ MLP layer1: split-bf16 MFMA, A = s (fp32, split on the fly) =======================
// out_hi/lo[z][m][0:200] = split(relu(s_z[m][0:600] @ W1 + b1)); B = Wt1 [256][608] pre-split.
__global__ __launch_bounds__(256) void mlp1_gemm_split(
    const float* __restrict__ A0, const float* __restrict__ A1,
    const unsigned short* __restrict__ Bhi, const unsigned short* __restrict__ Blo,
    const float* __restrict__ bias,
    unsigned short* __restrict__ OutHi, unsigned short* __restrict__ OutLo)
{
  __shared__ unsigned short sAhi[128 * LROW], sAlo[128 * LROW];
  __shared__ unsigned short sBhi[128 * LROW], sBlo[128 * LROW];
  const int z = blockIdx.z;
  const float* __restrict__ A = z ? A1 : A0;
  unsigned short* __restrict__ oH = OutHi + (size_t)z * RS * HID;
  unsigned short* __restrict__ oL = OutLo + (size_t)z * RS * HID;
  const int m0 = blockIdx.x * 128, n0 = blockIdx.y * 128;
  const int tid = threadIdx.x, lane = tid & 63;
  const int w = tid >> 6, wr = w >> 1, wc = w & 1;
  const int fr = lane & 15, kg = lane >> 4;

  f32x4 acc[4][4];
#pragma unroll
  for (int mi = 0; mi < 4; ++mi)
#pragma unroll
    for (int ni = 0; ni < 4; ++ni) acc[mi][ni] = (f32x4){0.f, 0.f, 0.f, 0.f};

  for (int k0 = 0; k0 < 608; k0 += 32) {
    __syncthreads();
#pragma unroll
    for (int it = 0; it < 4; ++it) {
      // ---- A: 128 rows x 8 half-chunks (4 fp32 each) -> split to hi/lo
      {
        const int t = it * 256 + tid;
        const int r = t >> 3, hc = t & 7;
        const int gk = k0 + hc * 4;
        float4 v = make_float4(0.f, 0.f, 0.f, 0.f);
        if (gk < INP) v = *(const float4*)(A + (size_t)(m0 + r) * INP + gk);
        ushort4 hi, lo;
        hi.x = f2bf(v.x); lo.x = f2bf(v.x - bf2f(hi.x));
        hi.y = f2bf(v.y); lo.y = f2bf(v.y - bf2f(hi.y));
        hi.z = f2bf(v.z); lo.z = f2bf(v.z - bf2f(hi.z));
        hi.w = f2bf(v.w); lo.w = f2bf(v.w - bf2f(hi.w));
        *(ushort4*)&sAhi[r * LROW + hc * 4] = hi;
        *(ushort4*)&sAlo[r * LROW + hc * 4] = lo;
      }
      // ---- B: pre-split, padded -> direct int4 copy (hi for it 0-1, lo for it 2-3)
      {
        const int t = it * 256 + tid;
        const bool isLo = t >> 9;
        const int rem = t & 511, r = rem >> 2, c = rem & 3;
        const unsigned short* src = isLo ? Blo : Bhi;
        unsigned short* dst = isLo ? sBlo : sBhi;
        *(int4*)&dst[r * LROW + c * 8] = *(const int4*)(src + (size_t)(n0 + r) * 608 + k0 + c * 8);
      }
    }
    __syncthreads();
    short8v ah[4], al[4], bh[4], bl[4];
#pragma unroll
    for (int mi = 0; mi < 4; ++mi) {
      const int row = wr * 64 + mi * 16 + fr;
      ah[mi] = *(const short8v*)&sAhi[row * LROW + kg * 8];
      al[mi] = *(const short8v*)&sAlo[row * LROW + kg * 8];
    }
#pragma unroll
    for (int ni = 0; ni < 4; ++ni) {
      const int row = wc * 64 + ni * 16 + fr;
      bh[ni] = *(const short8v*)&sBhi[row * LROW + kg * 8];
      bl[ni] = *(const short8v*)&sBlo[row * LROW + kg * 8];
    }
#pragma unroll
    for (int mi = 0; mi < 4; ++mi)
#pragma unroll
      for (int ni = 0; ni < 4; ++ni) {
        acc[mi][ni] = __builtin_amdgcn_mfma_f32_16x16x32_bf16(ah[mi], bh[ni], acc[mi][ni], 0, 0, 0);
        acc[mi][ni] = __builtin_amdgcn_mfma_f32_16x16x32_bf16(ah[mi], bl[ni], acc[mi][ni], 0, 0, 0);
        acc[mi][ni] = __builtin_amdgcn_mfma_f32_16x16x32_bf16(al[mi], bh[ni], acc[mi][ni], 0, 0, 0);
      }
  }
  // epilogue: relu(acc+bias) -> split bf16
#pragma unroll
  for (int ni = 0; ni < 4; ++ni) {
    const int gn = n0 + wc * 64 + ni * 16 + fr;
    if (gn < HID) {
      const float bs = bias[gn];
#pragma unroll
      for (int mi = 0; mi < 4; ++mi) {
#pragma unroll
        for (int r = 0; r < 4; ++r) {
          const int gm = m0 + wr * 64 + mi * 16 + kg * 4 + r;
          float v = relu(acc[mi][ni][r] + bs);
          unsigned short hi = f2bf(v);
          oH[(size_t)gm * HID + gn] = hi;
          oL[(size_t)gm * HID + gn] = f2bf(v - bf2f(hi));
        }
      }
    }
  }
}

// ============ Unified split-bf16 MFMA GEMM (pre-split A and B), KP=224 =========================
// SPLIT_OUT=true : Out = split(relu(acc+bias)), N-guarded (mlp layer2)
// SPLIT_OUT=false: OutF = acc (fp32, no guard)                  (e_gemm)
template <bool SPLIT_OUT>
__global__ __launch_bounds__(256) void split_gemm_bf16(
    const unsigned short* __restrict__ Ahi, const unsigned short* __restrict__ Alo,
    int lda, size_t aZ,
    const unsigned short* __restrict__ Bhi, const unsigned short* __restrict__ Blo,
    int ldb, size_t bZ,
    int a_chunks, int b_chunks,
    const float* __restrict__ bias,
    unsigned short* __restrict__ OutHi, unsigned short* __restrict__ OutLo,
    float* __restrict__ OutF, int ldo, size_t oZ)
{
  __shared__ unsigned short sAhi[128 * LROW], sAlo[128 * LROW];
  __shared__ unsigned short sBhi[128 * LROW], sBlo[128 * LROW];
  const int z = blockIdx.z;
  const unsigned short* __restrict__ Ah = Ahi + (size_t)z * aZ;
  const unsigned short* __restrict__ Al = Alo + (size_t)z * aZ;
  const unsigned short* __restrict__ Bh = Bhi + (size_t)z * bZ;
  const unsigned short* __restrict__ Bl = Blo + (size_t)z * bZ;
  const int m0 = blockIdx.x * 128, n0 = blockIdx.y * 128;
  const int tid = threadIdx.x, lane = tid & 63;
  const int w = tid >> 6, wr = w >> 1, wc = w & 1;
  const int fr = lane & 15, kg = lane >> 4;

  f32x4 acc[4][4];
#pragma unroll
  for (int mi = 0; mi < 4; ++mi)
#pragma unroll
    for (int ni = 0; ni < 4; ++ni) acc[mi][ni] = (f32x4){0.f, 0.f, 0.f, 0.f};

  for (int k0 = 0; k0 < 224; k0 += 32) {
    const int kc0 = k0 >> 3;
    __syncthreads();
#pragma unroll
    for (int it = 0; it < 4; ++it) {
      const int t = it * 256 + tid;
      const bool isLo = t >> 9;             // uniform per it
      const int rem = t & 511, r = rem >> 2, c = rem & 3;
      const bool av = (kc0 + c) < a_chunks;
      const bool bv = (kc0 + c) < b_chunks;
      int4 va = make_int4(0, 0, 0, 0), vb = make_int4(0, 0, 0, 0);
      if (av) va = *(const int4*)((isLo ? Al : Ah) + (size_t)(m0 + r) * lda + k0 + c * 8);
      if (bv) vb = *(const int4*)((isLo ? Bl : Bh) + (size_t)(n0 + r) * ldb + k0 + c * 8);
      unsigned short* dA = isLo ? sAlo : sAhi;
      unsigned short* dB = isLo ? sBlo : sBhi;
      *(int4*)&dA[r * LROW + c * 8] = va;
      *(int4*)&dB[r * LROW + c * 8] = vb;
    }
    __syncthreads();
    short8v ah[4], al[4], bh[4], bl[4];
#pragma unroll
    for (int mi = 0; mi < 4; ++mi) {
      const int row = wr * 64 + mi * 16 + fr;
      ah[mi] = *(const short8v*)&sAhi[row * LROW + kg * 8];
      al[mi] = *(const short8v*)&sAlo[row * LROW + kg * 8];
    }
#pragma unroll
    for (int ni = 0; ni < 4; ++ni) {
      const int row = wc * 64 + ni * 16 + fr;
      bh[ni] = *(const short8v*)&sBhi[row * LROW + kg * 8];
      bl[ni] = *(const short8v*)&sBlo[row * LROW + kg * 8];
    }
#pragma unroll
    for (int mi = 0; mi < 4; ++mi)
#pragma unroll
      for (int ni = 0; ni < 4; ++ni) {
        acc[mi][ni] = __builtin_amdgcn_mfma_f32_16x16x32_bf16(ah[mi], bh[ni], acc[mi][ni], 0, 0, 0);
        acc[mi][ni] = __builtin_amdgcn_mfma_f32_16x16x32_bf16(ah[mi], bl[ni], acc[mi][ni], 0, 0, 0);
        acc[mi][ni] = __builtin_amdgcn_mfma_f32_16x16x32_bf16(al[mi], bh[ni], acc[mi][ni], 0, 0, 0);
      }
  }
#pragma unroll
  for (int ni = 0; ni < 4; ++ni) {
    const int gn = n0 + wc * 64 + ni * 16 + fr;
    if (!SPLIT_OUT || gn < HID) {
      const float bs = SPLIT_OUT ? bias[gn] : 0.f;
#pragma unroll
      for (int mi = 0; mi < 4; ++mi) {
#pragma unroll
        for (int r = 0; r < 4; ++r) {
          const int gm = m0 + wr * 64 + mi * 16 + kg * 4 + r;
          if (SPLIT_OUT) {
            float v = relu(acc[mi][ni][r] + bs);
            unsigned short hi = f2bf(v);
            OutHi[(size_t)z * oZ + (size_t)gm * ldo + gn] = hi;
            OutLo[(size_t)z * oZ + (size_t)gm * ldo + gn] = f2bf(v - bf2f(hi));
          } else {
            OutF[(size_t)z * oZ + (size_t)gm * ldo + gn] = acc[mi][ni][r];
          }
        }
      }
    }
  }
}

// ---------------- fused row stats + P_beta: one E read, bf16 P out ----------------
__global__ __launch_bounds__(256) void row_stats_pbeta(
    const float* __restrict__ E, const float* __restrict__ mask2,
    unsigned short* __restrict__ Pb)
{
  const int wid = threadIdx.x >> 6, lane = threadIdx.x & 63;
  const int r = blockIdx.x * 4 + wid;
  const int b = r >> 10;
  const float* __restrict__ row = E + (size_t)r * LL;
  const float* __restrict__ m2 = mask2 + b * LL;
  float v[16];
  float mx = -INFINITY;
#pragma unroll
  for (int i = 0; i < 4; ++i) {
    const int m = lane * 4 + i * 256;
    float4 e4 = *(const float4*)(row + m);
    float4 k4 = *(const float4*)(m2 + m);
    v[i * 4 + 0] = e4.x * k4.x; v[i * 4 + 1] = e4.y * k4.y;
    v[i * 4 + 2] = e4.z * k4.z; v[i * 4 + 3] = e4.w * k4.w;
    mx = fmaxf(mx, fmaxf(fmaxf(v[i * 4], v[i * 4 + 1]), fmaxf(v[i * 4 + 2], v[i * 4 + 3])));
  }
#pragma unroll
  for (int off = 32; off; off >>= 1) mx = fmaxf(mx, __shfl_xor(mx, off));
  float s = 0.f;
#pragma unroll
  for (int i = 0; i < 16; ++i) s += __expf(v[i] - mx);
#pragma unroll
  for (int off = 32; off; off >>= 1) s += __shfl_xor(s, off);
  const float ri = 1.f / s;
#pragma unroll
  for (int i = 0; i < 4; ++i) {
    const int m = lane * 4 + i * 256;
    ushort4 o;
    o.x = f2bf(__expf(v[i * 4 + 0] - mx) * ri);
    o.y = f2bf(__expf(v[i * 4 + 1] - mx) * ri);
    o.z = f2bf(__expf(v[i * 4 + 2] - mx) * ri);
    o.w = f2bf(__expf(v[i * 4 + 3] - mx) * ri);
    *(ushort4*)(Pb + (size_t)r * LL + m) = o;
  }
}

// ---------------- column stats (alpha softmax over l), two-pass ----------------
__global__ __launch_bounds__(256) void col_stats_p1(
    const float* __restrict__ E, const float* __restrict__ mask1,
    float* __restrict__ pmax, float* __restrict__ psum)
{
  const int b = blockIdx.z, lc = blockIdx.y;
  const int m = blockIdx.x * 256 + threadIdx.x;
  const float* __restrict__ e = E + (size_t)b * LL * LL;
  const float* __restrict__ m1 = mask1 + b * LL;
  float mx = -INFINITY, s = 0.f;
#pragma unroll 4
  for (int l = lc * 256; l < lc * 256 + 256; ++l) {
    const float v = e[(size_t)l * LL + m] * m1[l];
    if (v > mx) { s = s * __expf(mx - v) + 1.f; mx = v; }
    else        { s += __expf(v - mx); }
  }
  const int idx = (b * 4 + lc) * LL + m;
  pmax[idx] = mx; psum[idx] = s;
}

__global__ __launch_bounds__(256) void col_stats_p2(
    const float* __restrict__ pmax, const float* __restrict__ psum,
    float* __restrict__ cmax, float* __restrict__ cinv)
{
  const int b = blockIdx.y;
  const int m = blockIdx.x * 256 + threadIdx.x;
  float M = -INFINITY;
#pragma unroll
  for (int i = 0; i < 4; ++i) M = fmaxf(M, pmax[(b * 4 + i) * LL + m]);
  float S = 0.f;
#pragma unroll
  for (int i = 0; i < 4; ++i) S += psum[(b * 4 + i) * LL + m] * __expf(pmax[(b * 4 + i) * LL + m] - M);
  cmax[(size_t)b * LL + m] = M;
  cinv[(size_t)b * LL + m] = 1.f / S;
}

// ---------------- P_alpha[m][l] (bf16, transposed) ----------------
__global__ __launch_bounds__(256) void palpha_kernel(
    const float* __restrict__ E, const float* __restrict__ mask1,
    const float* __restrict__ cmax, const float* __restrict__ cinv,
    unsigned short* __restrict__ Pa)
{
  __shared__ float T[64][65];
  const int b = blockIdx.z;
  const int l0 = blockIdx.y * 64, m0 = blockIdx.x * 64;
  const int tid = threadIdx.x;
  const int rr = tid >> 4, c4 = (tid & 15) * 4;
  const float4 cm = *(const float4*)(cmax + b * LL + m0 + c4);
  const float4 ci = *(const float4*)(cinv + b * LL + m0 + c4);
#pragma unroll
  for (int it = 0; it < 4; ++it) {
    const int lloc = rr + it * 16;
    const int l = l0 + lloc;
    const float mk = mask1[b * LL + l];
    const float4 ev = *(const float4*)(E + ((size_t)b * LL + l) * LL + m0 + c4);
    T[c4 + 0][lloc] = __expf(ev.x * mk - cm.x) * ci.x;
    T[c4 + 1][lloc] = __expf(ev.y * mk - cm.y) * ci.y;
    T[c4 + 2][lloc] = __expf(ev.z * mk - cm.z) * ci.z;
    T[c4 + 3][lloc] = __expf(ev.w * mk - cm.w) * ci.w;
  }
  __syncthreads();
#pragma unroll
  for (int it = 0; it < 4; ++it) {
    const int mloc = rr + it * 16;
    ushort4 o;
    o.x = f2bf(T[mloc][c4 + 0]);
    o.y = f2bf(T[mloc][c4 + 1]);
    o.z = f2bf(T[mloc][c4 + 2]);
    o.w = f2bf(T[mloc][c4 + 3]);
    *(ushort4*)(Pa + ((size_t)b * LL + m0 + mloc) * LL + l0 + c4) = o;
  }
}

// ---------------- s transpose+cast: S[b][l][0:600] fp32 -> St[b][0:640][l] bf16 ----------------
__global__ __launch_bounds__(256) void s_transpose(
    const float* __restrict__ S, unsigned short* __restrict__ St)
{
  __shared__ float T[64][65];
  const int b = blockIdx.z;
  const int l0 = blockIdx.y * 64, d0 = blockIdx.x * 64;
  const int tid = threadIdx.x;
  const int rr = tid >> 4, c4 = (tid & 15) * 4;
#pragma unroll
  for (int it = 0; it < 4; ++it) {
    const int lloc = rr + it * 16;
    const int l = l0 + lloc;
    float4 v = make_float4(0.f, 0.f, 0.f, 0.f);
    if (d0 + c4 < INP) v = *(const float4*)(S + ((size_t)b * LL + l) * INP + d0 + c4);
    T[c4 + 0][lloc] = v.x; T[c4 + 1][lloc] = v.y;
    T[c4 + 2][lloc] = v.z; T[c4 + 3][lloc] = v.w;
  }
  __syncthreads();
#pragma unroll
  for (int it = 0; it < 4; ++it) {
    const int dloc = rr + it * 16;
    ushort4 o;
    o.x = f2bf(T[dloc][c4 + 0]);
    o.y = f2bf(T[dloc][c4 + 1]);
    o.z = f2bf(T[dloc][c4 + 2]);
    o.w = f2bf(T[dloc][c4 + 3]);
    *(ushort4*)(St + ((size_t)b * DPAD + d0 + dloc) * LL + l0 + c4) = o;
  }
}

// ---------------- bf16 MFMA GEMM: Out[b][m][d] = (sum_k Ap[m][k]*Bt[d][k]) * scale[b][m] -------
__global__ __launch_bounds__(256) void attn_gemm_bf16(
    const unsigned short* __restrict__ Ap, const unsigned short* __restrict__ Bt,
    const float* __restrict__ scale, float* __restrict__ Out)
{
  __shared__ int4 sA4[1024];   // 128 rows x 8 x 16B, swizzled: idx = row*8 + (kc ^ (row&7))
  __shared__ int4 sB4[1024];
  __shared__ float s_sc[128];
  const int b  = blockIdx.z;
  const int n0 = blockIdx.x * 128;
  const int m0 = blockIdx.y * 128;
  const int tid = threadIdx.x;
  const int lane = tid & 63;
  const int w = tid >> 6;
  const int wr = w >> 1, wc = w & 1;

  const unsigned short* __restrict__ A  = Ap + (size_t)b * LL * LL;
  const unsigned short* __restrict__ Bp = Bt + (size_t)b * DPAD * LL;

  if (tid < 128) s_sc[tid] = scale[b * LL + m0 + tid];

  f32x4 acc[4][4];
#pragma unroll
  for (int mi = 0; mi < 4; ++mi)
#pragma unroll
    for (int ni = 0; ni < 4; ++ni)
      acc[mi][ni] = (f32x4){0.f, 0.f, 0.f, 0.f};

  const int kc = tid & 7;
  const int rbase = tid >> 3;
  const int fr = lane & 15;
  const int kg = lane >> 4;

  for (int k0 = 0; k0 < LL; k0 += 64) {
    __syncthreads();
#pragma unroll
    for (int it = 0; it < 4; ++it) {
      const int r = rbase + 32 * it;
      sA4[r * 8 + (kc ^ (r & 7))] = *(const int4*)(A  + (size_t)(m0 + r) * LL + k0 + kc * 8);
      sB4[r * 8 + (kc ^ (r & 7))] = *(const int4*)(Bp + (size_t)(n0 + r) * LL + k0 + kc * 8);
    }
    __syncthreads();
#pragma unroll
    for (int kk = 0; kk < 2; ++kk) {
      short8v a[4], bf[4];
#pragma unroll
      for (int mi = 0; mi < 4; ++mi) {
        const int row = wr * 64 + mi * 16 + fr;
        a[mi] = *(const short8v*)&sA4[row * 8 + ((kk * 4 + kg) ^ (row & 7))];
      }
#pragma unroll
      for (int ni = 0; ni < 4; ++ni) {
        const int row = wc * 64 + ni * 16 + fr;
        bf[ni] = *(const short8v*)&sB4[row * 8 + ((kk * 4 + kg) ^ (row & 7))];
      }
#pragma unroll
      for (int mi = 0; mi < 4; ++mi)
#pragma unroll
        for (int ni = 0; ni < 4; ++ni)
          acc[mi][ni] = __builtin_amdgcn_mfma_f32_16x16x32_bf16(a[mi], bf[ni], acc[mi][ni], 0, 0, 0);
    }
  }

#pragma unroll
  for (int mi = 0; mi < 4; ++mi) {
#pragma unroll
    for (int ni = 0; ni < 4; ++ni) {
      const int col = n0 + wc * 64 + ni * 16 + fr;
      if (col < INP) {
#pragma unroll
        for (int r = 0; r < 4; ++r) {
          const int mrow = wr * 64 + mi * 16 + kg * 4 + r;
          Out[((size_t)b * LL + m0 + mrow) * INP + col] = acc[mi][ni][r] * s_sc[mrow];
        }
      }
    }
  }
}

// =================== fp32 fallback kernels (round-1 path, used only if ws is small) ============
__global__ __launch_bounds__(256) void mlp_gemm(
    const float* __restrict__ A0, const float* __restrict__ A1,
    const float* __restrict__ W,  const float* __restrict__ bias,
    float* __restrict__ Out, int K)
{
  __shared__ __align__(16) float sA[KT][BM];
  __shared__ __align__(16) float sB[KT][BN];
  const int z = blockIdx.z;
  const float* __restrict__ A = z ? A1 : A0;
  float* __restrict__ out = Out + (size_t)z * RS * HID;
  const int m0 = blockIdx.x * BM;
  const int n0 = blockIdx.y * BN;
  const int tid = threadIdx.x;
  const int tx = tid & 15, ty = tid >> 4;
  const int am = tid & 127, akg = (tid >> 7) * 4;
  const int bn = (tid & 31) * 4, bkk = tid >> 5;

  float acc[8][8] = {};
  for (int k0 = 0; k0 < K; k0 += KT) {
    float4 av = *(const float4*)(A + (size_t)(m0 + am) * K + k0 + akg);
    sA[akg + 0][am] = av.x; sA[akg + 1][am] = av.y;
    sA[akg + 2][am] = av.z; sA[akg + 3][am] = av.w;
    const int gn = n0 + bn;
    float4 bv = make_float4(0.f, 0.f, 0.f, 0.f);
    if (gn < HID) bv = *(const float4*)(W + (size_t)(k0 + bkk) * HID + gn);
    *(float4*)&sB[bkk][bn] = bv;
    __syncthreads();
    micro_8x8(sA, sB, acc, tx, ty);
    __syncthreads();
  }
#pragma unroll
  for (int i = 0; i < 8; ++i) {
    const int m = m0 + ty * 8 + i;
#pragma unroll
    for (int j4 = 0; j4 < 8; j4 += 4) {
      const int n = n0 + tx * 8 + j4;
      if (n < HID) {
        float4 v;
        v.x = relu(acc[i][j4 + 0] + bias[n + 0]);
        v.y = relu(acc[i][j4 + 1] + bias[n + 1]);
        v.z = relu(acc[i][j4 + 2] + bias[n + 2]);
        v.w = relu(acc[i][j4 + 3] + bias[n + 3]);
        *(float4*)(out + (size_t)m * HID + n) = v;
      }
    }
  }
}

__global__ __launch_bounds__(256) void e_gemm(
    const float* __restrict__ H1, const float* __restrict__ H2, float* __restrict__ E)
{
  __shared__ __align__(16) float sA[KT][BM];
  __shared__ __align__(16) float sB[KT][BN];
  const int b = blockIdx.z;
  const float* __restrict__ A  = H1 + (size_t)b * LL * HID;
  const float* __restrict__ Bp = H2 + (size_t)b * LL * HID;
  float* __restrict__ e = E + (size_t)b * LL * LL;
  const int l0 = blockIdx.x * BM;
  const int m0 = blockIdx.y * BN;
  const int tid = threadIdx.x;
  const int tx = tid & 15, ty = tid >> 4;
  const int rr = tid & 127, kg = (tid >> 7) * 4;

  float acc[8][8] = {};
  for (int k0 = 0; k0 < HID; k0 += KT) {
    float4 av = *(const float4*)(A + (size_t)(l0 + rr) * HID + k0 + kg);
    sA[kg + 0][rr] = av.x; sA[kg + 1][rr] = av.y;
    sA[kg + 2][rr] = av.z; sA[kg + 3][rr] = av.w;
    float4 bv = *(const float4*)(Bp + (size_t)(m0 + rr) * HID + k0 + kg);
    sB[kg + 0][rr] = bv.x; sB[kg + 1][rr] = bv.y;
    sB[kg + 2][rr] = bv.z; sB[kg + 3][rr] = bv.w;
    __syncthreads();
    micro_8x8(sA, sB, acc, tx, ty);
    __syncthreads();
  }
#pragma unroll
  for (int i = 0; i < 8; ++i) {
    float* erow = e + (size_t)(l0 + ty * 8 + i) * LL + m0 + tx * 8;
    *(float4*)(erow)     = make_float4(acc[i][0], acc[i][1], acc[i][2], acc[i][3]);
    *(float4*)(erow + 4) = make_float4(acc[i][4], acc[i][5], acc[i][6], acc[i][7]);
  }
}

__global__ __launch_bounds__(256) void row_stats(
    const float* __restrict__ E, const float* __restrict__ mask2,
    float* __restrict__ rmax, float* __restrict__ rinv)
{
  const int wid = threadIdx.x >> 6, lane = threadIdx.x & 63;
  const int r = blockIdx.x * 4 + wid;
  const int b = r >> 10;
  const float* __restrict__ row = E + (size_t)r * LL;
  const float* __restrict__ m2 = mask2 + b * LL;
  float v[16];
  float mx = -INFINITY;
#pragma unroll
  for (int i = 0; i < 4; ++i) {
    const int m = lane * 4 + i * 256;
    float4 e4 = *(const float4*)(row + m);
    float4 k4 = *(const float4*)(m2 + m);
    v[i * 4 + 0] = e4.x * k4.x; v[i * 4 + 1] = e4.y * k4.y;
    v[i * 4 + 2] = e4.z * k4.z; v[i * 4 + 3] = e4.w * k4.w;
    mx = fmaxf(mx, fmaxf(fmaxf(v[i * 4], v[i * 4 + 1]), fmaxf(v[i * 4 + 2], v[i * 4 + 3])));
  }
#pragma unroll
  for (int off = 32; off; off >>= 1) mx = fmaxf(mx, __shfl_xor(mx, off));
  float s = 0.f;
#pragma unroll
  for (int i = 0; i < 16; ++i) s += __expf(v[i] - mx);
#pragma unroll
  for (int off = 32; off; off >>= 1) s += __shfl_xor(s, off);
  if (lane == 0) { rmax[r] = mx; rinv[r] = 1.f / s; }
}

__global__ __launch_bounds__(256) void alphas_gemm(
    const float* __restrict__ E, const float* __restrict__ S1,
    const float* __restrict__ mask1, const float* __restrict__ mask2,
    const float* __restrict__ cmax, const float* __restrict__ cinv,
    float* __restrict__ OutA)
{
  __shared__ __align__(16) float sA[KT][BM];
  __shared__ __align__(16) float sB[KT][BN];
  __shared__ __align__(16) float s_cm[BM], s_ci[BM], s_m2[BM];
  const int b = blockIdx.z;
  const float* __restrict__ e  = E  + (size_t)b * LL * LL;
  const float* __restrict__ s1 = S1 + (size_t)b * LL * INP;
  const int m0 = blockIdx.x * BM;
  const int d0 = blockIdx.y * BN;
  const int tid = threadIdx.x;
  const int tx = tid & 15, ty = tid >> 4;
  if (tid < BM) {
    s_cm[tid] = cmax[b * LL + m0 + tid];
    s_ci[tid] = cinv[b * LL + m0 + tid];
    s_m2[tid] = mask2[b * LL + m0 + tid];
  }
  __syncthreads();
  const int cc = (tid & 31) * 4, kk_ = tid >> 5;

  float acc[8][8] = {};
  for (int k0 = 0; k0 < LL; k0 += KT) {
    const int l = k0 + kk_;
    const float mk = mask1[b * LL + l];
    float4 ev = *(const float4*)(e + (size_t)l * LL + m0 + cc);
    float4 av;
    av.x = __expf(ev.x * mk - s_cm[cc + 0]) * s_ci[cc + 0];
    av.y = __expf(ev.y * mk - s_cm[cc + 1]) * s_ci[cc + 1];
    av.z = __expf(ev.z * mk - s_cm[cc + 2]) * s_ci[cc + 2];
    av.w = __expf(ev.w * mk - s_cm[cc + 3]) * s_ci[cc + 3];
    *(float4*)&sA[kk_][cc] = av;
    const int gd = d0 + cc;
    float4 bv = make_float4(0.f, 0.f, 0.f, 0.f);
    if (gd < INP) bv = *(const float4*)(s1 + (size_t)l * INP + gd);
    *(float4*)&sB[kk_][cc] = bv;
    __syncthreads();
    micro_8x8(sA, sB, acc, tx, ty);
    __syncthreads();
  }
#pragma unroll
  for (int i = 0; i < 8; ++i) {
    const int m = m0 + ty * 8 + i;
    const float mm = s_m2[ty * 8 + i];
    float* orow = OutA + ((size_t)b * LL + m) * INP;
#pragma unroll
    for (int j4 = 0; j4 < 8; j4 += 4) {
      const int d = d0 + tx * 8 + j4;
      if (d < INP) {
        *(float4*)(orow + d) = make_float4(acc[i][j4] * mm, acc[i][j4 + 1] * mm,
                                           acc[i][j4 + 2] * mm, acc[i][j4 + 3] * mm);
      }
    }
  }
}

__global__ __launch_bounds__(256) void betas_gemm(
    const float* __restrict__ E, const float* __restrict__ S2,
    const float* __restrict__ mask1, const float* __restrict__ mask2,
    const float* __restrict__ rmax, const float* __restrict__ rinv,
    float* __restrict__ OutB)
{
  __shared__ __align__(16) float sA[KT][BM];
  __shared__ __align__(16) float sB[KT][BN];
  __shared__ __align__(16) float s_rm[BM], s_ri[BM], s_m1[BM];
  const int b = blockIdx.z;
  const float* __restrict__ e  = E  + (size_t)b * LL * LL;
  const float* __restrict__ s2 = S2 + (size_t)b * LL * INP;
  const int l0 = blockIdx.x * BM;
  const int d0 = blockIdx.y * BN;
  const int tid = threadIdx.x;
  const int tx = tid & 15, ty = tid >> 4;
  if (tid < BM) {
    s_rm[tid] = rmax[b * LL + l0 + tid];
    s_ri[tid] = rinv[b * LL + l0 + tid];
    s_m1[tid] = mask1[b * LL + l0 + tid];
  }
  __syncthreads();
  const int al = tid & 127, akg = (tid >> 7) * 4;
  const int cc = (tid & 31) * 4, kk_ = tid >> 5;

  float acc[8][8] = {};
  for (int k0 = 0; k0 < LL; k0 += KT) {
    float4 ev = *(const float4*)(e + (size_t)(l0 + al) * LL + k0 + akg);
    float4 mk = *(const float4*)(mask2 + b * LL + k0 + akg);
    const float rm = s_rm[al], ri = s_ri[al];
    sA[akg + 0][al] = __expf(ev.x * mk.x - rm) * ri;
    sA[akg + 1][al] = __expf(ev.y * mk.y - rm) * ri;
    sA[akg + 2][al] = __expf(ev.z * mk.z - rm) * ri;
    sA[akg + 3][al] = __expf(ev.w * mk.w - rm) * ri;
    const int gd = d0 + cc;
    float4 bv = make_float4(0.f, 0.f, 0.f, 0.f);
    if (gd < INP) bv = *(const float4*)(s2 + (size_t)(k0 + kk_) * INP + gd);
    *(float4*)&sB[kk_][cc] = bv;
    __syncthreads();
    micro_8x8(sA, sB, acc, tx, ty);
    __syncthreads();
  }
#pragma unroll
  for (int i = 0; i < 8; ++i) {
    const int l = l0 + ty * 8 + i;
    const float mm = s_m1[ty * 8 + i];
    float* orow = OutB + ((size_t)b * LL + l) * INP;
#pragma unroll
    for (int j4 = 0; j4 < 8; j4 += 4) {
      const int d = d0 + tx * 8 + j4;
      if (d < INP) {
        *(float4*)(orow + d) = make_float4(acc[i][j4] * mm, acc[i][j4 + 1] * mm,
                                           acc[i][j4 + 2] * mm, acc[i][j4 + 3] * mm);
      }
    }
  }
}

} // namespace

extern "C" void kernel_launch(void* const* d_in, const int* in_sizes, int n_in,
                              void* d_out, int out_size, void* d_ws, size_t ws_size,
                              hipStream_t stream)
{
  const float* s1    = (const float*)d_in[0];
  const float* s2    = (const float*)d_in[1];
  const float* mask1 = (const float*)d_in[2];
  const float* mask2 = (const float*)d_in[3];
  const float* W1    = (const float*)d_in[4];
  const float* b1    = (const float*)d_in[5];
  const float* W2    = (const float*)d_in[6];
  const float* b2    = (const float*)d_in[7];

  char* ws = (char*)d_ws;
  float* outA = (float*)d_out;
  float* outB = outA + (size_t)BB * LL * INP;

  // -------- fast-path workspace layout (bytes), lifetime-packed --------
  // [0]            hmid_hi (26,214,400) | hmid_lo (26,214,400)        -> dead after mlp2
  // [52,428,800]   h_hi (26,214,400)    | h_lo (26,214,400)           -> dead after e_gemm
  // [104,857,600]  E (134,217,728)                                    -> dead after palpha
  //    (Wt1/Wt2 overlay the E region before e_gemm; s1t/s2t overlay after palpha)
  // [239,075,328]  Pb (67,108,864)                                    -> end 306,184,192
  // Pa overlays [0, 67,108,864) after e_gemm; stats at [67,108,864] (dead-h region).
  const size_t off_hmid = 0;
  const size_t off_h    = 52428800;
  const size_t off_E    = 104857600;
  const size_t off_Pb   = 239075328;
  const size_t TOTAL    = 306184192;

  if (ws_size >= TOTAL) {
    unsigned short* hmid_hi = (unsigned short*)(ws + off_hmid);
    unsigned short* hmid_lo = hmid_hi + (size_t)2 * RS * HID;
    unsigned short* h_hi    = (unsigned short*)(ws + off_h);
    unsigned short* h_lo    = h_hi + (size_t)2 * RS * HID;
    float* E = (float*)(ws + off_E);
    // Wt arrays overlay the (not-yet-written) E region
    unsigned short* Wt1hi = (unsigned short*)(ws + off_E);
    unsigned short* Wt1lo = Wt1hi + (size_t)256 * 608;
    unsigned short* Wt2hi = Wt1lo + (size_t)256 * 608;
    unsigned short* Wt2lo = Wt2hi + (size_t)256 * 224;
    unsigned short* Pb = (unsigned short*)(ws + off_Pb);
    unsigned short* Pa = (unsigned short*)(ws + 0);
    float* stats = (float*)(ws + 67108864);   // inside dead h region
    float* cmax = stats;
    float* cinv = cmax + RS;
    float* pmax = cinv + RS;
    float* psum = pmax + (size_t)BB * 4 * LL;
    unsigned short* s1t = (unsigned short*)(ws + off_E);                       // after palpha
    unsigned short* s2t = s1t + (size_t)BB * DPAD * LL;

    // 1) W transpose+split (tiny)
    wt_prep<<<dim3(3, 256), 256, 0, stream>>>(W1, Wt1hi, Wt1lo, INP, 608);
    wt_prep<<<dim3(1, 256), 256, 0, stream>>>(W2, Wt2hi, Wt2lo, HID, 224);
    // 2) MLP layer 1 (split MFMA, A=fp32 s)
    mlp1_gemm_split<<<dim3(RS / 128, 2, 2), 256, 0, stream>>>(
        s1, s2, Wt1hi, Wt1lo, b1, hmid_hi, hmid_lo);
    // 3) MLP layer 2 (split MFMA, pre-split A)
    split_gemm_bf16<true><<<dim3(RS / 128, 2, 2), 256, 0, stream>>>(
        hmid_hi, hmid_lo, HID, (size_t)RS * HID,
        Wt2hi, Wt2lo, 224, 0,
        25, 28, b2, h_hi, h_lo, nullptr, HID, (size_t)RS * HID);
    // 4) e = h1 @ h2^T (split MFMA)
    split_gemm_bf16<false><<<dim3(8, 8, BB), 256, 0, stream>>>(
        h_hi, h_lo, HID, (size_t)LL * HID,
        h_hi + (size_t)RS * HID, h_lo + (size_t)RS * HID, HID, (size_t)LL * HID,
        25, 25, nullptr, nullptr, nullptr, E, LL, (size_t)LL * LL);
    // 5) softmax stats + P matrices
    row_stats_pbeta<<<dim3(RS / 4), 256, 0, stream>>>(E, mask2, Pb);
    col_stats_p1<<<dim3(4, 4, BB), 256, 0, stream>>>(E, mask1, pmax, psum);
    col_stats_p2<<<dim3(4, BB), 256, 0, stream>>>(pmax, psum, cmax, cinv);
    palpha_kernel<<<dim3(16, 16, BB), 256, 0, stream>>>(E, mask1, cmax, cinv, Pa);  // E dead after
    // 6) s transposes (overlay E region)
    s_transpose<<<dim3(10, 16, BB), 256, 0, stream>>>(s1, s1t);
    s_transpose<<<dim3(10, 16, BB), 256, 0, stream>>>(s2, s2t);
    // 7) outputs
    attn_gemm_bf16<<<dim3(5, 8, BB), 256, 0, stream>>>(Pb, s2t, mask1, outB);
    attn_gemm_bf16<<<dim3(5, 8, BB), 256, 0, stream>>>(Pa, s1t, mask2, outA);
  } else {
    // -------- fallback: round-1 fp32 path (188 MB) --------
    float* h    = (float*)ws;
    float* hmid = h + (size_t)2 * RS * HID;
    float* E    = hmid;
    float* stats = hmid + (size_t)BB * LL * LL;
    float* rmax = stats;
    float* rinv = rmax + RS;
    float* cmax = rinv + RS;
    float* cinv = cmax + RS;
    float* pmax = cinv + RS;
    float* psum = pmax + (size_t)BB * 4 * LL;

    mlp_gemm<<<dim3(RS / BM, 2, 2), 256, 0, stream>>>(s1, s2, W1, b1, hmid, INP);
    mlp_gemm<<<dim3(RS / BM, 2, 2), 256, 0, stream>>>(hmid, hmid + (size_t)RS * HID, W2, b2, h, HID);
    e_gemm<<<dim3(LL / BM, LL / BN, BB), 256, 0, stream>>>(h, h + (size_t)RS * HID, E);
    row_stats<<<dim3(RS / 4), 256, 0, stream>>>(E, mask2, rmax, rinv);
    col_stats_p1<<<dim3(4, 4, BB), 256, 0, stream>>>(E, mask1, pmax, psum);
    col_stats_p2<<<dim3(4, BB), 256, 0, stream>>>(pmax, psum, cmax, cinv);
    alphas_gemm<<<dim3(LL / BM, (INP + BN - 1) / BN, BB), 256, 0, stream>>>(
        E, s1, mask1, mask2, cmax, cinv, outA);
    betas_gemm<<<dim3(LL / BM, (INP + BN - 1) / BN, BB), 256, 0, stream>>>(
        E, s2, mask1, mask2, rmax, rinv, outB);
  }

  (void)in_sizes; (void)n_in; (void)out_size;
}

// Round 4
// 926.424 us; speedup vs baseline: 2.0281x; 1.0213x over previous
//
#include <hip/hip_runtime.h>
#include <math.h>

namespace {

constexpr int BB  = 32;    // batch
constexpr int LL  = 1024;  // sequence length
constexpr int INP = 600;
constexpr int HID = 200;
constexpr int RS  = BB * LL;   // 32768 rows per stream
constexpr int DPAD = 640;      // padded d-dim for bf16 transposed s

constexpr int BM = 128, BN = 128, KT = 8;   // (fallback path tiles)

typedef __attribute__((ext_vector_type(8))) short short8v;           // bf16x8 fragment
typedef __attribute__((ext_vector_type(8))) unsigned short ushort8v;
typedef __attribute__((ext_vector_type(4))) float f32x4;

__device__ __forceinline__ float relu(float x) { return fmaxf(x, 0.f); }

__device__ __forceinline__ unsigned short f2bf(float x) {
  union { float f; unsigned int u; } v; v.f = x;
  unsigned int r = v.u + 0x7FFFu + ((v.u >> 16) & 1u);   // RNE
  return (unsigned short)(r >> 16);
}
__device__ __forceinline__ float bf2f(unsigned short h) {
  union { unsigned int u; float f; } v; v.u = ((unsigned int)h) << 16;
  return v.f;
}

// async global->LDS, 16B per lane; LDS dest = wave-uniform base + lane*16
__device__ __forceinline__ void gload16(const void* g, void* l) {
  __builtin_amdgcn_global_load_lds((const __attribute__((address_space(1))) void*)g,
                                   (__attribute__((address_space(3))) void*)l, 16, 0, 0);
}

// ============ W transpose + split prep: W[K][200] fp32 -> Wt_hi/lo[256][KP] bf16, zero-pad ======
__global__ __launch_bounds__(256) void wt_prep(
    const float* __restrict__ W, unsigned short* __restrict__ Whi, unsigned short* __restrict__ Wlo,
    int K, int KP)
{
  const int k = blockIdx.x * 256 + threadIdx.x;
  const int n = blockIdx.y;              // 0..255 (rows >=200 zero)
  if (k >= KP) return;
  float v = (k < K && n < HID) ? W[(size_t)k * HID + n] : 0.f;
  unsigned short hi = f2bf(v);
  unsigned short lo = f2bf(v - bf2f(hi));
  Whi[(size_t)n * KP + k] = hi;
  Wlo[(size_t)n * KP + k] = lo;
}

// ============ Unified split-bf16 MFMA GEMM ======================================================
// MLP=true : A = fp32 (A0/A1 per stream, split in regs), B = pre-split bf16 via global_load_lds,
//            epilogue = relu(acc+bias) -> fp32, col guard gn<HID.
// MLP=false: A,B fp32 z-strided (both reg-split), epilogue = raw fp32 (e = h1 @ h2^T).
// Tile 128x128, 4 waves (2x2), BK=64. LDS slot = row*8 + (chunk ^ (row&7)), hi at [0,1024),
// lo at [1024,2048) int4 slots.
template <bool MLP>
__global__ __launch_bounds__(256) void splitmm(
    const float* __restrict__ A0, const float* __restrict__ A1, long aZ, int lda, int ka,
    const float* __restrict__ Bf, long bZ,
    const unsigned short* __restrict__ Bhi, const unsigned short* __restrict__ Blo,
    int ldb, int kb, int ksteps,
    const float* __restrict__ bias,
    float* __restrict__ Out, int ldo, long oZ)
{
  __shared__ int4 sA[2048];
  __shared__ int4 sB[2048];
  const int z = blockIdx.z;
  const int m0 = blockIdx.x * 128, n0 = blockIdx.y * 128;
  const int tid = threadIdx.x, lane = tid & 63, w = tid >> 6;
  const int wr = w >> 1, wc = w & 1, fr = lane & 15, kg = lane >> 4;

  const float* __restrict__ A = MLP ? (z ? A1 : A0) : (A0 + (size_t)z * aZ);
  const float* __restrict__ Bp = MLP ? (const float*)nullptr : (Bf + (size_t)z * bZ);

  const int ar = tid >> 1, aseg = tid & 1;   // staging: row, k-half (32k)

  f32x4 acc[4][4];
#pragma unroll
  for (int mi = 0; mi < 4; ++mi)
#pragma unroll
    for (int ni = 0; ni < 4; ++ni) acc[mi][ni] = (f32x4){0.f, 0.f, 0.f, 0.f};

  for (int ks = 0; ks < ksteps; ++ks) {
    const int k0 = ks * 64;
    __syncthreads();
    // ---- A stage: fp32 -> (hi,lo) in regs -> LDS
#pragma unroll
    for (int u = 0; u < 4; ++u) {
      const int c = aseg * 4 + u;
      const int gk = k0 + c * 8;
      float4 v0 = make_float4(0.f, 0.f, 0.f, 0.f), v1 = v0;
      if (gk < ka) {
        const float* p = A + (size_t)(m0 + ar) * lda + gk;
        v0 = *(const float4*)p;
        v1 = *(const float4*)(p + 4);
      }
      ushort8v hv, lv;
      hv[0] = f2bf(v0.x); lv[0] = f2bf(v0.x - bf2f(hv[0]));
      hv[1] = f2bf(v0.y); lv[1] = f2bf(v0.y - bf2f(hv[1]));
      hv[2] = f2bf(v0.z); lv[2] = f2bf(v0.z - bf2f(hv[2]));
      hv[3] = f2bf(v0.w); lv[3] = f2bf(v0.w - bf2f(hv[3]));
      hv[4] = f2bf(v1.x); lv[4] = f2bf(v1.x - bf2f(hv[4]));
      hv[5] = f2bf(v1.y); lv[5] = f2bf(v1.y - bf2f(hv[5]));
      hv[6] = f2bf(v1.z); lv[6] = f2bf(v1.z - bf2f(hv[6]));
      hv[7] = f2bf(v1.w); lv[7] = f2bf(v1.w - bf2f(hv[7]));
      const int slot = ar * 8 + (c ^ (ar & 7));
      *(ushort8v*)&sA[slot] = hv;
      *(ushort8v*)&sA[1024 + slot] = lv;
    }
    // ---- B stage
    if (MLP) {
      // pre-split, zero-padded: pure async global->LDS, inverse-swizzled source
#pragma unroll
      for (int i = 0; i < 8; ++i) {
        const int s = w * 512 + i * 64 + lane;
        const int tens = s >> 10, rem = s & 1023, r = rem >> 3, kc = rem & 7;
        const int gc = kc ^ (r & 7);
        const unsigned short* src = (tens ? Blo : Bhi) + (size_t)(n0 + r) * ldb + k0 + gc * 8;
        gload16(src, (char*)sB + ((size_t)(w * 512 + i * 64)) * 16);
      }
    } else {
#pragma unroll
      for (int u = 0; u < 4; ++u) {
        const int c = aseg * 4 + u;
        const int gk = k0 + c * 8;
        float4 v0 = make_float4(0.f, 0.f, 0.f, 0.f), v1 = v0;
        if (gk < kb) {
          const float* p = Bp + (size_t)(n0 + ar) * ldb + gk;
          v0 = *(const float4*)p;
          v1 = *(const float4*)(p + 4);
        }
        ushort8v hv, lv;
        hv[0] = f2bf(v0.x); lv[0] = f2bf(v0.x - bf2f(hv[0]));
        hv[1] = f2bf(v0.y); lv[1] = f2bf(v0.y - bf2f(hv[1]));
        hv[2] = f2bf(v0.z); lv[2] = f2bf(v0.z - bf2f(hv[2]));
        hv[3] = f2bf(v0.w); lv[3] = f2bf(v0.w - bf2f(hv[3]));
        hv[4] = f2bf(v1.x); lv[4] = f2bf(v1.x - bf2f(hv[4]));
        hv[5] = f2bf(v1.y); lv[5] = f2bf(v1.y - bf2f(hv[5]));
        hv[6] = f2bf(v1.z); lv[6] = f2bf(v1.z - bf2f(hv[6]));
        hv[7] = f2bf(v1.w); lv[7] = f2bf(v1.w - bf2f(hv[7]));
        const int slot = ar * 8 + (c ^ (ar & 7));
        *(ushort8v*)&sB[slot] = hv;
        *(ushort8v*)&sB[1024 + slot] = lv;
      }
    }
    __syncthreads();
    // ---- compute: 2 k-substeps x 48 MFMA
#pragma unroll
    for (int kk = 0; kk < 2; ++kk) {
      short8v ah[4], al[4], bh[4], bl[4];
#pragma unroll
      for (int mi = 0; mi < 4; ++mi) {
        const int row = wr * 64 + mi * 16 + fr;
        const int idx = row * 8 + ((kk * 4 + kg) ^ (row & 7));
        ah[mi] = *(const short8v*)&sA[idx];
        al[mi] = *(const short8v*)&sA[1024 + idx];
      }
#pragma unroll
      for (int ni = 0; ni < 4; ++ni) {
        const int row = wc * 64 + ni * 16 + fr;
        const int idx = row * 8 + ((kk * 4 + kg) ^ (row & 7));
        bh[ni] = *(const short8v*)&sB[idx];
        bl[ni] = *(const short8v*)&sB[1024 + idx];
      }
#pragma unroll
      for (int mi = 0; mi < 4; ++mi)
#pragma unroll
        for (int ni = 0; ni < 4; ++ni) {
          acc[mi][ni] = __builtin_amdgcn_mfma_f32_16x16x32_bf16(ah[mi], bh[ni], acc[mi][ni], 0, 0, 0);
          acc[mi][ni] = __builtin_amdgcn_mfma_f32_16x16x32_bf16(ah[mi], bl[ni], acc[mi][ni], 0, 0, 0);
          acc[mi][ni] = __builtin_amdgcn_mfma_f32_16x16x32_bf16(al[mi], bh[ni], acc[mi][ni], 0, 0, 0);
        }
    }
  }
  // ---- epilogue (C/D: col = lane&15, row = (lane>>4)*4 + reg)
#pragma unroll
  for (int ni = 0; ni < 4; ++ni) {
    const int gn = n0 + wc * 64 + ni * 16 + fr;
    if (!MLP || gn < HID) {
      const float bs = MLP ? bias[gn] : 0.f;
#pragma unroll
      for (int mi = 0; mi < 4; ++mi) {
#pragma unroll
        for (int r = 0; r < 4; ++r) {
          const int gm = m0 + wr * 64 + mi * 16 + kg * 4 + r;
          float v = acc[mi][ni][r] + bs;
          if (MLP) v = relu(v);
          Out[(size_t)z * oZ + (size_t)gm * ldo + gn] = v;
        }
      }
    }
  }
}

// ---------------- fused row stats + P_beta: one E read, bf16 P out ----------------
__global__ __launch_bounds__(256) void row_stats_pbeta(
    const float* __restrict__ E, const float* __restrict__ mask2,
    unsigned short* __restrict__ Pb)
{
  const int wid = threadIdx.x >> 6, lane = threadIdx.x & 63;
  const int r = blockIdx.x * 4 + wid;
  const int b = r >> 10;
  const float* __restrict__ row = E + (size_t)r * LL;
  const float* __restrict__ m2 = mask2 + b * LL;
  float v[16];
  float mx = -INFINITY;
#pragma unroll
  for (int i = 0; i < 4; ++i) {
    const int m = lane * 4 + i * 256;
    float4 e4 = *(const float4*)(row + m);
    float4 k4 = *(const float4*)(m2 + m);
    v[i * 4 + 0] = e4.x * k4.x; v[i * 4 + 1] = e4.y * k4.y;
    v[i * 4 + 2] = e4.z * k4.z; v[i * 4 + 3] = e4.w * k4.w;
    mx = fmaxf(mx, fmaxf(fmaxf(v[i * 4], v[i * 4 + 1]), fmaxf(v[i * 4 + 2], v[i * 4 + 3])));
  }
#pragma unroll
  for (int off = 32; off; off >>= 1) mx = fmaxf(mx, __shfl_xor(mx, off));
  float s = 0.f;
#pragma unroll
  for (int i = 0; i < 16; ++i) s += __expf(v[i] - mx);
#pragma unroll
  for (int off = 32; off; off >>= 1) s += __shfl_xor(s, off);
  const float ri = 1.f / s;
#pragma unroll
  for (int i = 0; i < 4; ++i) {
    const int m = lane * 4 + i * 256;
    ushort4 o;
    o.x = f2bf(__expf(v[i * 4 + 0] - mx) * ri);
    o.y = f2bf(__expf(v[i * 4 + 1] - mx) * ri);
    o.z = f2bf(__expf(v[i * 4 + 2] - mx) * ri);
    o.w = f2bf(__expf(v[i * 4 + 3] - mx) * ri);
    *(ushort4*)(Pb + (size_t)r * LL + m) = o;
  }
}

// ---------------- column stats (alpha softmax over l), two-pass ----------------
__global__ __launch_bounds__(256) void col_stats_p1(
    const float* __restrict__ E, const float* __restrict__ mask1,
    float* __restrict__ pmax, float* __restrict__ psum)
{
  const int b = blockIdx.z, lc = blockIdx.y;
  const int m = blockIdx.x * 256 + threadIdx.x;
  const float* __restrict__ e = E + (size_t)b * LL * LL;
  const float* __restrict__ m1 = mask1 + b * LL;
  float mx = -INFINITY, s = 0.f;
#pragma unroll 4
  for (int l = lc * 256; l < lc * 256 + 256; ++l) {
    const float v = e[(size_t)l * LL + m] * m1[l];
    if (v > mx) { s = s * __expf(mx - v) + 1.f; mx = v; }
    else        { s += __expf(v - mx); }
  }
  const int idx = (b * 4 + lc) * LL + m;
  pmax[idx] = mx; psum[idx] = s;
}

__global__ __launch_bounds__(256) void col_stats_p2(
    const float* __restrict__ pmax, const float* __restrict__ psum,
    float* __restrict__ cmax, float* __restrict__ cinv)
{
  const int b = blockIdx.y;
  const int m = blockIdx.x * 256 + threadIdx.x;
  float M = -INFINITY;
#pragma unroll
  for (int i = 0; i < 4; ++i) M = fmaxf(M, pmax[(b * 4 + i) * LL + m]);
  float S = 0.f;
#pragma unroll
  for (int i = 0; i < 4; ++i) S += psum[(b * 4 + i) * LL + m] * __expf(pmax[(b * 4 + i) * LL + m] - M);
  cmax[(size_t)b * LL + m] = M;
  cinv[(size_t)b * LL + m] = 1.f / S;
}

// ---------------- P_alpha[m][l] (bf16, transposed) ----------------
__global__ __launch_bounds__(256) void palpha_kernel(
    const float* __restrict__ E, const float* __restrict__ mask1,
    const float* __restrict__ cmax, const float* __restrict__ cinv,
    unsigned short* __restrict__ Pa)
{
  __shared__ float T[64][65];
  const int b = blockIdx.z;
  const int l0 = blockIdx.y * 64, m0 = blockIdx.x * 64;
  const int tid = threadIdx.x;
  const int rr = tid >> 4, c4 = (tid & 15) * 4;
  const float4 cm = *(const float4*)(cmax + b * LL + m0 + c4);
  const float4 ci = *(const float4*)(cinv + b * LL + m0 + c4);
#pragma unroll
  for (int it = 0; it < 4; ++it) {
    const int lloc = rr + it * 16;
    const int l = l0 + lloc;
    const float mk = mask1[b * LL + l];
    const float4 ev = *(const float4*)(E + ((size_t)b * LL + l) * LL + m0 + c4);
    T[c4 + 0][lloc] = __expf(ev.x * mk - cm.x) * ci.x;
    T[c4 + 1][lloc] = __expf(ev.y * mk - cm.y) * ci.y;
    T[c4 + 2][lloc] = __expf(ev.z * mk - cm.z) * ci.z;
    T[c4 + 3][lloc] = __expf(ev.w * mk - cm.w) * ci.w;
  }
  __syncthreads();
#pragma unroll
  for (int it = 0; it < 4; ++it) {
    const int mloc = rr + it * 16;
    ushort4 o;
    o.x = f2bf(T[mloc][c4 + 0]);
    o.y = f2bf(T[mloc][c4 + 1]);
    o.z = f2bf(T[mloc][c4 + 2]);
    o.w = f2bf(T[mloc][c4 + 3]);
    *(ushort4*)(Pa + ((size_t)b * LL + m0 + mloc) * LL + l0 + c4) = o;
  }
}

// ---------------- s transpose+cast: S[b][l][0:600] fp32 -> St[b][0:640][l] bf16 ----------------
__global__ __launch_bounds__(256) void s_transpose(
    const float* __restrict__ S, unsigned short* __restrict__ St)
{
  __shared__ float T[64][65];
  const int b = blockIdx.z;
  const int l0 = blockIdx.y * 64, d0 = blockIdx.x * 64;
  const int tid = threadIdx.x;
  const int rr = tid >> 4, c4 = (tid & 15) * 4;
#pragma unroll
  for (int it = 0; it < 4; ++it) {
    const int lloc = rr + it * 16;
    const int l = l0 + lloc;
    float4 v = make_float4(0.f, 0.f, 0.f, 0.f);
    if (d0 + c4 < INP) v = *(const float4*)(S + ((size_t)b * LL + l) * INP + d0 + c4);
    T[c4 + 0][lloc] = v.x; T[c4 + 1][lloc] = v.y;
    T[c4 + 2][lloc] = v.z; T[c4 + 3][lloc] = v.w;
  }
  __syncthreads();
#pragma unroll
  for (int it = 0; it < 4; ++it) {
    const int dloc = rr + it * 16;
    ushort4 o;
    o.x = f2bf(T[dloc][c4 + 0]);
    o.y = f2bf(T[dloc][c4 + 1]);
    o.z = f2bf(T[dloc][c4 + 2]);
    o.w = f2bf(T[dloc][c4 + 3]);
    *(ushort4*)(St + ((size_t)b * DPAD + d0 + dloc) * LL + l0 + c4) = o;
  }
}

// ---------------- bf16 MFMA GEMM: Out[b][m][d] = (sum_k Ap[m][k]*Bt[d][k]) * scale[b][m] -------
// A tensor = LDS slots [0,1024), B = [1024,2048); staged via global_load_lds.
__global__ __launch_bounds__(256) void attn_gemm_bf16(
    const unsigned short* __restrict__ Ap, const unsigned short* __restrict__ Bt,
    const float* __restrict__ scale, float* __restrict__ Out)
{
  __shared__ int4 sAB[2048];
  __shared__ float s_sc[128];
  const int b  = blockIdx.z;
  const int n0 = blockIdx.x * 128;
  const int m0 = blockIdx.y * 128;
  const int tid = threadIdx.x;
  const int lane = tid & 63;
  const int w = tid >> 6;
  const int wr = w >> 1, wc = w & 1;
  const int fr = lane & 15, kg = lane >> 4;

  const unsigned short* __restrict__ A  = Ap + (size_t)b * LL * LL;
  const unsigned short* __restrict__ Bp = Bt + (size_t)b * DPAD * LL;

  if (tid < 128) s_sc[tid] = scale[b * LL + m0 + tid];

  f32x4 acc[4][4];
#pragma unroll
  for (int mi = 0; mi < 4; ++mi)
#pragma unroll
    for (int ni = 0; ni < 4; ++ni)
      acc[mi][ni] = (f32x4){0.f, 0.f, 0.f, 0.f};

  for (int k0 = 0; k0 < LL; k0 += 64) {
    __syncthreads();
#pragma unroll
    for (int i = 0; i < 8; ++i) {
      const int s = w * 512 + i * 64 + lane;
      const int tens = s >> 10, rem = s & 1023, r = rem >> 3, kc = rem & 7;
      const int gc = kc ^ (r & 7);
      const unsigned short* src = tens ? (Bp + (size_t)(n0 + r) * LL + k0 + gc * 8)
                                       : (A  + (size_t)(m0 + r) * LL + k0 + gc * 8);
      gload16(src, (char*)sAB + ((size_t)(w * 512 + i * 64)) * 16);
    }
    __syncthreads();
#pragma unroll
    for (int kk = 0; kk < 2; ++kk) {
      short8v a[4], bf[4];
#pragma unroll
      for (int mi = 0; mi < 4; ++mi) {
        const int row = wr * 64 + mi * 16 + fr;
        a[mi] = *(const short8v*)&sAB[row * 8 + ((kk * 4 + kg) ^ (row & 7))];
      }
#pragma unroll
      for (int ni = 0; ni < 4; ++ni) {
        const int row = wc * 64 + ni * 16 + fr;
        bf[ni] = *(const short8v*)&sAB[1024 + row * 8 + ((kk * 4 + kg) ^ (row & 7))];
      }
#pragma unroll
      for (int mi = 0; mi < 4; ++mi)
#pragma unroll
        for (int ni = 0; ni < 4; ++ni)
          acc[mi][ni] = __builtin_amdgcn_mfma_f32_16x16x32_bf16(a[mi], bf[ni], acc[mi][ni], 0, 0, 0);
    }
  }

#pragma unroll
  for (int mi = 0; mi < 4; ++mi) {
#pragma unroll
    for (int ni = 0; ni < 4; ++ni) {
      const int col = n0 + wc * 64 + ni * 16 + fr;
      if (col < INP) {
#pragma unroll
        for (int r = 0; r < 4; ++r) {
          const int mrow = wr * 64 + mi * 16 + kg * 4 + r;
          Out[((size_t)b * LL + m0 + mrow) * INP + col] = acc[mi][ni][r] * s_sc[mrow];
        }
      }
    }
  }
}

// =================== fp32 fallback kernels (round-1 path, only if ws too small) ================
__device__ __forceinline__ void micro_8x8(const float (&sA)[KT][BM], const float (&sB)[KT][BN],
                                          float (&acc)[8][8], int tx, int ty)
{
#pragma unroll
  for (int kk = 0; kk < KT; ++kk) {
    float4 a0 = *(const float4*)&sA[kk][ty * 8];
    float4 a1 = *(const float4*)&sA[kk][ty * 8 + 4];
    float4 b0 = *(const float4*)&sB[kk][tx * 8];
    float4 b1 = *(const float4*)&sB[kk][tx * 8 + 4];
    float ar[8] = {a0.x, a0.y, a0.z, a0.w, a1.x, a1.y, a1.z, a1.w};
    float br[8] = {b0.x, b0.y, b0.z, b0.w, b1.x, b1.y, b1.z, b1.w};
#pragma unroll
    for (int i = 0; i < 8; ++i)
#pragma unroll
      for (int j = 0; j < 8; ++j)
        acc[i][j] = fmaf(ar[i], br[j], acc[i][j]);
  }
}

__global__ __launch_bounds__(256) void mlp_gemm(
    const float* __restrict__ A0, const float* __restrict__ A1,
    const float* __restrict__ W,  const float* __restrict__ bias,
    float* __restrict__ Out, int K)
{
  __shared__ __align__(16) float sA[KT][BM];
  __shared__ __align__(16) float sB[KT][BN];
  const int z = blockIdx.z;
  const float* __restrict__ A = z ? A1 : A0;
  float* __restrict__ out = Out + (size_t)z * RS * HID;
  const int m0 = blockIdx.x * BM;
  const int n0 = blockIdx.y * BN;
  const int tid = threadIdx.x;
  const int tx = tid & 15, ty = tid >> 4;
  const int am = tid & 127, akg = (tid >> 7) * 4;
  const int bn = (tid & 31) * 4, bkk = tid >> 5;

  float acc[8][8] = {};
  for (int k0 = 0; k0 < K; k0 += KT) {
    float4 av = *(const float4*)(A + (size_t)(m0 + am) * K + k0 + akg);
    sA[akg + 0][am] = av.x; sA[akg + 1][am] = av.y;
    sA[akg + 2][am] = av.z; sA[akg + 3][am] = av.w;
    const int gn = n0 + bn;
    float4 bv = make_float4(0.f, 0.f, 0.f, 0.f);
    if (gn < HID) bv = *(const float4*)(W + (size_t)(k0 + bkk) * HID + gn);
    *(float4*)&sB[bkk][bn] = bv;
    __syncthreads();
    micro_8x8(sA, sB, acc, tx, ty);
    __syncthreads();
  }
#pragma unroll
  for (int i = 0; i < 8; ++i) {
    const int m = m0 + ty * 8 + i;
#pragma unroll
    for (int j4 = 0; j4 < 8; j4 += 4) {
      const int n = n0 + tx * 8 + j4;
      if (n < HID) {
        float4 v;
        v.x = relu(acc[i][j4 + 0] + bias[n + 0]);
        v.y = relu(acc[i][j4 + 1] + bias[n + 1]);
        v.z = relu(acc[i][j4 + 2] + bias[n + 2]);
        v.w = relu(acc[i][j4 + 3] + bias[n + 3]);
        *(float4*)(out + (size_t)m * HID + n) = v;
      }
    }
  }
}

__global__ __launch_bounds__(256) void e_gemm(
    const float* __restrict__ H1, const float* __restrict__ H2, float* __restrict__ E)
{
  __shared__ __align__(16) float sA[KT][BM];
  __shared__ __align__(16) float sB[KT][BN];
  const int b = blockIdx.z;
  const float* __restrict__ A  = H1 + (size_t)b * LL * HID;
  const float* __restrict__ Bp = H2 + (size_t)b * LL * HID;
  float* __restrict__ e = E + (size_t)b * LL * LL;
  const int l0 = blockIdx.x * BM;
  const int m0 = blockIdx.y * BN;
  const int tid = threadIdx.x;
  const int tx = tid & 15, ty = tid >> 4;
  const int rr = tid & 127, kg = (tid >> 7) * 4;

  float acc[8][8] = {};
  for (int k0 = 0; k0 < HID; k0 += KT) {
    float4 av = *(const float4*)(A + (size_t)(l0 + rr) * HID + k0 + kg);
    sA[kg + 0][rr] = av.x; sA[kg + 1][rr] = av.y;
    sA[kg + 2][rr] = av.z; sA[kg + 3][rr] = av.w;
    float4 bv = *(const float4*)(Bp + (size_t)(m0 + rr) * HID + k0 + kg);
    sB[kg + 0][rr] = bv.x; sB[kg + 1][rr] = bv.y;
    sB[kg + 2][rr] = bv.z; sB[kg + 3][rr] = bv.w;
    __syncthreads();
    micro_8x8(sA, sB, acc, tx, ty);
    __syncthreads();
  }
#pragma unroll
  for (int i = 0; i < 8; ++i) {
    float* erow = e + (size_t)(l0 + ty * 8 + i) * LL + m0 + tx * 8;
    *(float4*)(erow)     = make_float4(acc[i][0], acc[i][1], acc[i][2], acc[i][3]);
    *(float4*)(erow + 4) = make_float4(acc[i][4], acc[i][5], acc[i][6], acc[i][7]);
  }
}

__global__ __launch_bounds__(256) void row_stats(
    const float* __restrict__ E, const float* __restrict__ mask2,
    float* __restrict__ rmax, float* __restrict__ rinv)
{
  const int wid = threadIdx.x >> 6, lane = threadIdx.x & 63;
  const int r = blockIdx.x * 4 + wid;
  const int b = r >> 10;
  const float* __restrict__ row = E + (size_t)r * LL;
  const float* __restrict__ m2 = mask2 + b * LL;
  float v[16];
  float mx = -INFINITY;
#pragma unroll
  for (int i = 0; i < 4; ++i) {
    const int m = lane * 4 + i * 256;
    float4 e4 = *(const float4*)(row + m);
    float4 k4 = *(const float4*)(m2 + m);
    v[i * 4 + 0] = e4.x * k4.x; v[i * 4 + 1] = e4.y * k4.y;
    v[i * 4 + 2] = e4.z * k4.z; v[i * 4 + 3] = e4.w * k4.w;
    mx = fmaxf(mx, fmaxf(fmaxf(v[i * 4], v[i * 4 + 1]), fmaxf(v[i * 4 + 2], v[i * 4 + 3])));
  }
#pragma unroll
  for (int off = 32; off; off >>= 1) mx = fmaxf(mx, __shfl_xor(mx, off));
  float s = 0.f;
#pragma unroll
  for (int i = 0; i < 16; ++i) s += __expf(v[i] - mx);
#pragma unroll
  for (int off = 32; off; off >>= 1) s += __shfl_xor(s, off);
  if (lane == 0) { rmax[r] = mx; rinv[r] = 1.f / s; }
}

__global__ __launch_bounds__(256) void alphas_gemm(
    const float* __restrict__ E, const float* __restrict__ S1,
    const float* __restrict__ mask1, const float* __restrict__ mask2,
    const float* __restrict__ cmax, const float* __restrict__ cinv,
    float* __restrict__ OutA)
{
  __shared__ __align__(16) float sA[KT][BM];
  __shared__ __align__(16) float sB[KT][BN];
  __shared__ __align__(16) float s_cm[BM], s_ci[BM], s_m2[BM];
  const int b = blockIdx.z;
  const float* __restrict__ e  = E  + (size_t)b * LL * LL;
  const float* __restrict__ s1 = S1 + (size_t)b * LL * INP;
  const int m0 = blockIdx.x * BM;
  const int d0 = blockIdx.y * BN;
  const int tid = threadIdx.x;
  const int tx = tid & 15, ty = tid >> 4;
  if (tid < BM) {
    s_cm[tid] = cmax[b * LL + m0 + tid];
    s_ci[tid] = cinv[b * LL + m0 + tid];
    s_m2[tid] = mask2[b * LL + m0 + tid];
  }
  __syncthreads();
  const int cc = (tid & 31) * 4, kk_ = tid >> 5;

  float acc[8][8] = {};
  for (int k0 = 0; k0 < LL; k0 += KT) {
    const int l = k0 + kk_;
    const float mk = mask1[b * LL + l];
    float4 ev = *(const float4*)(e + (size_t)l * LL + m0 + cc);
    float4 av;
    av.x = __expf(ev.x * mk - s_cm[cc + 0]) * s_ci[cc + 0];
    av.y = __expf(ev.y * mk - s_cm[cc + 1]) * s_ci[cc + 1];
    av.z = __expf(ev.z * mk - s_cm[cc + 2]) * s_ci[cc + 2];
    av.w = __expf(ev.w * mk - s_cm[cc + 3]) * s_ci[cc + 3];
    *(float4*)&sA[kk_][cc] = av;
    const int gd = d0 + cc;
    float4 bv = make_float4(0.f, 0.f, 0.f, 0.f);
    if (gd < INP) bv = *(const float4*)(s1 + (size_t)l * INP + gd);
    *(float4*)&sB[kk_][cc] = bv;
    __syncthreads();
    micro_8x8(sA, sB, acc, tx, ty);
    __syncthreads();
  }
#pragma unroll
  for (int i = 0; i < 8; ++i) {
    const int m = m0 + ty * 8 + i;
    const float mm = s_m2[ty * 8 + i];
    float* orow = OutA + ((size_t)b * LL + m) * INP;
#pragma unroll
    for (int j4 = 0; j4 < 8; j4 += 4) {
      const int d = d0 + tx * 8 + j4;
      if (d < INP) {
        *(float4*)(orow + d) = make_float4(acc[i][j4] * mm, acc[i][j4 + 1] * mm,
                                           acc[i][j4 + 2] * mm, acc[i][j4 + 3] * mm);
      }
    }
  }
}

__global__ __launch_bounds__(256) void betas_gemm(
    const float* __restrict__ E, const float* __restrict__ S2,
    const float* __restrict__ mask1, const float* __restrict__ mask2,
    const float* __restrict__ rmax, const float* __restrict__ rinv,
    float* __restrict__ OutB)
{
  __shared__ __align__(16) float sA[KT][BM];
  __shared__ __align__(16) float sB[KT][BN];
  __shared__ __align__(16) float s_rm[BM], s_ri[BM], s_m1[BM];
  const int b = blockIdx.z;
  const float* __restrict__ e  = E  + (size_t)b * LL * LL;
  const float* __restrict__ s2 = S2 + (size_t)b * LL * INP;
  const int l0 = blockIdx.x * BM;
  const int d0 = blockIdx.y * BN;
  const int tid = threadIdx.x;
  const int tx = tid & 15, ty = tid >> 4;
  if (tid < BM) {
    s_rm[tid] = rmax[b * LL + l0 + tid];
    s_ri[tid] = rinv[b * LL + l0 + tid];
    s_m1[tid] = mask1[b * LL + l0 + tid];
  }
  __syncthreads();
  const int al = tid & 127, akg = (tid >> 7) * 4;
  const int cc = (tid & 31) * 4, kk_ = tid >> 5;

  float acc[8][8] = {};
  for (int k0 = 0; k0 < LL; k0 += KT) {
    float4 ev = *(const float4*)(e + (size_t)(l0 + al) * LL + k0 + akg);
    float4 mk = *(const float4*)(mask2 + b * LL + k0 + akg);
    const float rm = s_rm[al], ri = s_ri[al];
    sA[akg + 0][al] = __expf(ev.x * mk.x - rm) * ri;
    sA[akg + 1][al] = __expf(ev.y * mk.y - rm) * ri;
    sA[akg + 2][al] = __expf(ev.z * mk.z - rm) * ri;
    sA[akg + 3][al] = __expf(ev.w * mk.w - rm) * ri;
    const int gd = d0 + cc;
    float4 bv = make_float4(0.f, 0.f, 0.f, 0.f);
    if (gd < INP) bv = *(const float4*)(s2 + (size_t)(k0 + kk_) * INP + gd);
    *(float4*)&sB[kk_][cc] = bv;
    __syncthreads();
    micro_8x8(sA, sB, acc, tx, ty);
    __syncthreads();
  }
#pragma unroll
  for (int i = 0; i < 8; ++i) {
    const int l = l0 + ty * 8 + i;
    const float mm = s_m1[ty * 8 + i];
    float* orow = OutB + ((size_t)b * LL + l) * INP;
#pragma unroll
    for (int j4 = 0; j4 < 8; j4 += 4) {
      const int d = d0 + tx * 8 + j4;
      if (d < INP) {
        *(float4*)(orow + d) = make_float4(acc[i][j4] * mm, acc[i][j4 + 1] * mm,
                                           acc[i][j4 + 2] * mm, acc[i][j4 + 3] * mm);
      }
    }
  }
}

} // namespace

extern "C" void kernel_launch(void* const* d_in, const int* in_sizes, int n_in,
                              void* d_out, int out_size, void* d_ws, size_t ws_size,
                              hipStream_t stream)
{
  const float* s1    = (const float*)d_in[0];
  const float* s2    = (const float*)d_in[1];
  const float* mask1 = (const float*)d_in[2];
  const float* mask2 = (const float*)d_in[3];
  const float* W1    = (const float*)d_in[4];
  const float* b1    = (const float*)d_in[5];
  const float* W2    = (const float*)d_in[6];
  const float* b2    = (const float*)d_in[7];

  char* ws = (char*)d_ws;
  float* outA = (float*)d_out;
  float* outB = outA + (size_t)BB * LL * INP;

  // -------- fast-path workspace layout (bytes), lifetime-packed --------
  // [0,          52,428,800)  hmid fp32 [2][RS][200]   -> dead after mlp2; Pa overlays [0,67.1M)
  // [52,428,800, 104,857,600) h    fp32 [2][RS][200]   -> dead after e; stats at 67,108,864
  // [104,857,600,239,075,328) E    fp32 [BB][LL][LL]   -> Wt overlays start (pre-e);
  //                                                       s1t/s2t overlay after palpha
  // [239,075,328,306,184,192) Pb   bf16 [BB][LL][LL]
  const size_t off_h  = 52428800;
  const size_t off_E  = 104857600;
  const size_t off_Pb = 239075328;
  const size_t TOTAL  = 306184192;

  if (ws_size >= TOTAL) {
    float* hmid = (float*)(ws + 0);
    float* h    = (float*)(ws + off_h);
    float* E    = (float*)(ws + off_E);
    unsigned short* Wt1hi = (unsigned short*)(ws + off_E);
    unsigned short* Wt1lo = Wt1hi + (size_t)256 * 640;
    unsigned short* Wt2hi = Wt1lo + (size_t)256 * 640;
    unsigned short* Wt2lo = Wt2hi + (size_t)256 * 256;
    unsigned short* Pb = (unsigned short*)(ws + off_Pb);
    unsigned short* Pa = (unsigned short*)(ws + 0);
    float* stats = (float*)(ws + 67108864);   // inside dead h region, after Pa end
    float* cmax = stats;
    float* cinv = cmax + RS;
    float* pmax = cinv + RS;
    float* psum = pmax + (size_t)BB * 4 * LL;
    unsigned short* s1t = (unsigned short*)(ws + off_E);          // after palpha (E dead)
    unsigned short* s2t = s1t + (size_t)BB * DPAD * LL;

    // 1) W transpose+split, zero-padded to K=640 / 256 (removes all B guards)
    wt_prep<<<dim3(3, 256), 256, 0, stream>>>(W1, Wt1hi, Wt1lo, INP, 640);
    wt_prep<<<dim3(1, 256), 256, 0, stream>>>(W2, Wt2hi, Wt2lo, HID, 256);
    // 2) MLP layer 1: A = s fp32 (reg-split), B = Wt1 via global_load_lds
    splitmm<true><<<dim3(RS / 128, 2, 2), 256, 0, stream>>>(
        s1, s2, 0, INP, INP, nullptr, 0, Wt1hi, Wt1lo, 640, 0, 10,
        b1, hmid, HID, (long)RS * HID);
    // 3) MLP layer 2: A = hmid fp32, B = Wt2
    splitmm<true><<<dim3(RS / 128, 2, 2), 256, 0, stream>>>(
        hmid, hmid + (size_t)RS * HID, 0, HID, HID, nullptr, 0, Wt2hi, Wt2lo, 256, 0, 4,
        b2, h, HID, (long)RS * HID);
    // 4) e = h1 @ h2^T (both fp32, reg-split)
    splitmm<false><<<dim3(8, 8, BB), 256, 0, stream>>>(
        h, nullptr, (long)LL * HID, HID, HID,
        h + (size_t)RS * HID, (long)LL * HID, nullptr, nullptr, HID, HID, 4,
        nullptr, E, LL, (long)LL * LL);
    // 5) softmax stats + P matrices
    row_stats_pbeta<<<dim3(RS / 4), 256, 0, stream>>>(E, mask2, Pb);
    col_stats_p1<<<dim3(4, 4, BB), 256, 0, stream>>>(E, mask1, pmax, psum);
    col_stats_p2<<<dim3(4, BB), 256, 0, stream>>>(pmax, psum, cmax, cinv);
    palpha_kernel<<<dim3(16, 16, BB), 256, 0, stream>>>(E, mask1, cmax, cinv, Pa);  // E dead
    // 6) s transposes (overlay E region)
    s_transpose<<<dim3(10, 16, BB), 256, 0, stream>>>(s1, s1t);
    s_transpose<<<dim3(10, 16, BB), 256, 0, stream>>>(s2, s2t);
    // 7) outputs
    attn_gemm_bf16<<<dim3(5, 8, BB), 256, 0, stream>>>(Pb, s2t, mask1, outB);
    attn_gemm_bf16<<<dim3(5, 8, BB), 256, 0, stream>>>(Pa, s1t, mask2, outA);
  } else {
    // -------- fallback: round-1 fp32 path (188 MB) --------
    float* h    = (float*)ws;
    float* hmid = h + (size_t)2 * RS * HID;
    float* E    = hmid;
    float* stats = hmid + (size_t)BB * LL * LL;
    float* rmax = stats;
    float* rinv = rmax + RS;
    float* cmax = rinv + RS;
    float* cinv = cmax + RS;
    float* pmax = cinv + RS;
    float* psum = pmax + (size_t)BB * 4 * LL;

    mlp_gemm<<<dim3(RS / BM, 2, 2), 256, 0, stream>>>(s1, s2, W1, b1, hmid, INP);
    mlp_gemm<<<dim3(RS / BM, 2, 2), 256, 0, stream>>>(hmid, hmid + (size_t)RS * HID, W2, b2, h, HID);
    e_gemm<<<dim3(LL / BM, LL / BN, BB), 256, 0, stream>>>(h, h + (size_t)RS * HID, E);
    row_stats<<<dim3(RS / 4), 256, 0, stream>>>(E, mask2, rmax, rinv);
    col_stats_p1<<<dim3(4, 4, BB), 256, 0, stream>>>(E, mask1, pmax, psum);
    col_stats_p2<<<dim3(4, BB), 256, 0, stream>>>(pmax, psum, cmax, cinv);
    alphas_gemm<<<dim3(LL / BM, (INP + BN - 1) / BN, BB), 256, 0, stream>>>(
        E, s1, mask1, mask2, cmax, cinv, outA);
    betas_gemm<<<dim3(LL / BM, (INP + BN - 1) / BN, BB), 256, 0, stream>>>(
        E, s2, mask1, mask2, rmax, rinv, outB);
  }

  (void)in_sizes; (void)n_in; (void)out_size;
}